// Round 14
// baseline (419.581 us; speedup 1.0000x reference)
//
#include <hip/hip_runtime.h>
#include <math.h>

// Problem constants
#define BB 16
#define TT 12
#define NN 1024
#define FF 128
#define BT 192
#define BTN 196608
#define CNT ((float)BTN)
#define T1SZ 1572864   // BT*8*16*64 elements

typedef unsigned short ushort_t;
typedef __attribute__((ext_vector_type(8))) short bf16x8;
typedef __attribute__((ext_vector_type(4))) float f32x4;

__device__ __forceinline__ ushort_t f2bf(float x) {
    union { float f; unsigned u; } c; c.f = x;
    unsigned r = c.u + 0x7fffu + ((c.u >> 16) & 1u);
    return (ushort_t)(r >> 16);
}
__device__ __forceinline__ float bf2f(ushort_t u) {
    union { unsigned u32; float f; } c; c.u32 = ((unsigned)u) << 16; return c.f;
}
// packed f32x2 -> bf16x2 via native v_cvt_pk_bf16_f32 (RNE), 1 VALU op.
__device__ __forceinline__ unsigned pk2(float a, float b) {
    unsigned r;
    asm("v_cvt_pk_bf16_f32 %0, %1, %2" : "=v"(r) : "v"(a), "v"(b));
    return r;
}
// tanh-form GELU
__device__ __forceinline__ float gelu_f(float x) {
    float u = x * x;
    float s = x * fmaf(u, -0.10294428f, -2.30220852f);
    float e = __builtin_amdgcn_exp2f(s);
    return x * __builtin_amdgcn_rcpf(1.0f + e);
}

// XOR-swizzle helper (k_vs1 only)
__device__ __forceinline__ char* swz256(void* base, int row, int byteoff) {
    return (char*)base + row * 256 + (byteoff ^ ((row & 7) << 4));
}

// ---------- aff[h,c,n] ----------
__global__ __launch_bounds__(256) void k_aff(const float* __restrict__ cores,
                                             const float* __restrict__ adaptive,
                                             float* __restrict__ aff) {
    int idx = blockIdx.x * 256 + threadIdx.x;
    int n  = idx & 1023;
    int hc = idx >> 10;
    int h  = hc >> 6;
    const float* cp = cores + hc * 16;
    const float* ap = adaptive + h * 16384 + n;
    float s = 0.f;
#pragma unroll
    for (int d = 0; d < 16; ++d) s = fmaf(cp[d], ap[d * 1024], s);
    aff[idx] = s * 0.25f;
}

// ---------- softmax over n -> bf16 a_n2c[h,c,n] ----------
__global__ __launch_bounds__(256) void k_sm_n(const float* __restrict__ aff,
                                              ushort_t* __restrict__ out) {
    int row = blockIdx.x;
    const float* p = aff + row * 1024;
    int t = threadIdx.x;
    __shared__ float red[8];
    float v0 = p[t], v1 = p[t + 256], v2 = p[t + 512], v3 = p[t + 768];
    float m = fmaxf(fmaxf(v0, v1), fmaxf(v2, v3));
#pragma unroll
    for (int off = 32; off >= 1; off >>= 1) m = fmaxf(m, __shfl_xor(m, off));
    if ((t & 63) == 0) red[t >> 6] = m;
    __syncthreads();
    m = fmaxf(fmaxf(red[0], red[1]), fmaxf(red[2], red[3]));
    v0 = expf(v0 - m); v1 = expf(v1 - m); v2 = expf(v2 - m); v3 = expf(v3 - m);
    float s = v0 + v1 + v2 + v3;
#pragma unroll
    for (int off = 32; off >= 1; off >>= 1) s += __shfl_xor(s, off);
    __syncthreads();
    if ((t & 63) == 0) red[4 + (t >> 6)] = s;
    __syncthreads();
    s = red[4] + red[5] + red[6] + red[7];
    float inv = 1.0f / s;
    out[row * 1024 + t]       = f2bf(v0 * inv);
    out[row * 1024 + t + 256] = f2bf(v1 * inv);
    out[row * 1024 + t + 512] = f2bf(v2 * inv);
    out[row * 1024 + t + 768] = f2bf(v3 * inv);
}

// ---------- softmax over c -> transposed bf16 a_c2nT[h][n][c] ----------
__global__ __launch_bounds__(256) void k_sm_c(const float* __restrict__ aff,
                                              ushort_t* __restrict__ a_c2nT) {
    __shared__ ushort_t tile[64][72];
    int b = blockIdx.x;
    int h = b >> 4, n0 = (b & 15) * 64;
    int t = threadIdx.x;
    int nl = t >> 2, q = t & 3;
    const float* p = aff + h * 65536 + n0 + nl;
    float v[16];
    float m = -1e30f;
#pragma unroll
    for (int i = 0; i < 16; ++i) {
        v[i] = p[(q * 16 + i) * 1024];
        m = fmaxf(m, v[i]);
    }
    m = fmaxf(m, __shfl_xor(m, 1));
    m = fmaxf(m, __shfl_xor(m, 2));
    float s = 0.f;
#pragma unroll
    for (int i = 0; i < 16; ++i) { v[i] = expf(v[i] - m); s += v[i]; }
    s += __shfl_xor(s, 1);
    s += __shfl_xor(s, 2);
    float inv = 1.0f / s;
#pragma unroll
    for (int i = 0; i < 16; ++i) tile[nl][q * 16 + i] = f2bf(v[i] * inv);
    __syncthreads();
    ushort_t* ob = a_c2nT + ((size_t)h * 1024 + n0) * 64;
    for (int i = t; i < 512; i += 256) {
        int r = i >> 3, cq = i & 7;
        *(bf16x8*)&ob[r * 64 + cq * 8] = *(bf16x8*)&tile[r][cq * 8];
    }
}

// ---------- Wv transpose -> bf16 WvT[128][128] ----------
__global__ __launch_bounds__(256) void k_wprep_v(const float* __restrict__ Wv,
                                                 ushort_t* __restrict__ WvT) {
    __shared__ float tile[64][65];
    int b = blockIdx.x;
    int r0 = (b >> 1) * 64, c0 = (b & 1) * 64;
    int t = threadIdx.x;
    for (int i = t; i < 4096; i += 256) {
        int r = i >> 6, c = i & 63;
        tile[r][c] = Wv[(size_t)(r0 + r) * 128 + c0 + c];
    }
    __syncthreads();
    for (int i = t; i < 4096; i += 256) {
        int c = i >> 6, r = i & 63;
        WvT[(size_t)(c0 + c) * 128 + r0 + r] = f2bf(tile[r][c]);
    }
}

// ---------- W1 fragment-pack: W1f[ch][w][kk][jn][lane]*8 ----------
__global__ __launch_bounds__(256) void k_wpack1(const float* __restrict__ W1,
                                                ushort_t* __restrict__ W1f) {
    int tid = blockIdx.x * 256 + threadIdx.x;   // < 32768
    int lane = tid & 63, jn = (tid >> 6) & 1, kk = (tid >> 7) & 7;
    int w = (tid >> 10) & 3, ch = tid >> 12;
    int lr = lane & 15, lg = lane >> 4;
    int n = ch * 128 + w * 32 + jn * 16 + lr;
    int kb = kk * 32 + lg * 8;
    ushort_t o[8];
#pragma unroll
    for (int e = 0; e < 8; ++e) o[e] = f2bf(W1[(size_t)(kb + e) * 1024 + n]);
    *(bf16x8*)&W1f[(size_t)tid * 8] = *(bf16x8*)o;
}

// ---------- W2 fragment-pack: W2f[ch][w][kk][jy][lane]*8 ----------
__global__ __launch_bounds__(256) void k_wpack2(const float* __restrict__ W2,
                                                ushort_t* __restrict__ W2f) {
    int tid = blockIdx.x * 256 + threadIdx.x;   // < 16384
    int lane = tid & 63, jy = (tid >> 6) & 1, kk = (tid >> 7) & 3;
    int w = (tid >> 9) & 3, ch = tid >> 11;
    int lr = lane & 15, lg = lane >> 4;
    int f = w * 32 + jy * 16 + lr;
    int kb = ch * 128 + kk * 32 + lg * 8;
    ushort_t o[8];
#pragma unroll
    for (int e = 0; e < 8; ++e) o[e] = f2bf(W2[(size_t)(kb + e) * 128 + f]);
    *(bf16x8*)&W2f[(size_t)tid * 8] = *(bf16x8*)o;
}

// ---------- fused v-proj + stage1, 4-way n-split ----------
__global__ __launch_bounds__(256) void k_vs1(const float* __restrict__ input,
                                             const ushort_t* __restrict__ WvT,
                                             const float* __restrict__ bv,
                                             const ushort_t* __restrict__ a_n2c,
                                             float* __restrict__ T1p) {
    __shared__ __align__(16) ushort_t as_lds[128 * 128];
    __shared__ __align__(16) ushort_t vsT[128 * 128];
    int bt = blockIdx.x;
    int part = blockIdx.y;
    int t = threadIdx.x, w = t >> 6, lane = t & 63, lr = lane & 15, lg = lane >> 4;

    f32x4 t1acc[2][4];
#pragma unroll
    for (int hl = 0; hl < 2; ++hl)
#pragma unroll
        for (int mi = 0; mi < 4; ++mi) t1acc[hl][mi] = (f32x4){0.f, 0.f, 0.f, 0.f};

    for (int c8 = part * 2; c8 < part * 2 + 2; ++c8) {
        int n0 = c8 * 128;
        __syncthreads();
        for (int j = 0; j < 16; ++j) {
            int i = j * 256 + t;
            int r = i >> 5, cq = i & 31;
            float4 f = *(const float4*)&input[((size_t)(bt * 1024 + n0 + r)) * 128 + cq * 4];
            uint2 o;
            o.x = pk2(f.x, f.y);
            o.y = pk2(f.z, f.w);
            *(uint2*)swz256(as_lds, r, cq * 8) = o;
        }
        __syncthreads();
        f32x4 vacc[2][8];
#pragma unroll
        for (int mi = 0; mi < 2; ++mi)
#pragma unroll
            for (int jn = 0; jn < 8; ++jn) {
                float bb = bv[jn * 16 + lr];
                vacc[mi][jn] = (f32x4){bb, bb, bb, bb};
            }
#pragma unroll
        for (int ks = 0; ks < 4; ++ks) {
            bf16x8 a[2];
#pragma unroll
            for (int mi = 0; mi < 2; ++mi)
                a[mi] = *(const bf16x8*)swz256(as_lds, w * 32 + mi * 16 + lr, ks * 64 + lg * 16);
#pragma unroll
            for (int jn = 0; jn < 8; ++jn) {
                bf16x8 bfr = *(const bf16x8*)&WvT[(size_t)(jn * 16 + lr) * 128 + ks * 32 + lg * 8];
#pragma unroll
                for (int mi = 0; mi < 2; ++mi)
                    vacc[mi][jn] = __builtin_amdgcn_mfma_f32_16x16x32_bf16(a[mi], bfr, vacc[mi][jn], 0, 0, 0);
            }
        }
#pragma unroll
        for (int mi = 0; mi < 2; ++mi)
#pragma unroll
            for (int jn = 0; jn < 8; ++jn) {
                uint2 o;
                o.x = pk2(vacc[mi][jn][0], vacc[mi][jn][1]);
                o.y = pk2(vacc[mi][jn][2], vacc[mi][jn][3]);
                *(uint2*)swz256(vsT, jn * 16 + lr, w * 64 + mi * 32 + lg * 8) = o;
            }
        __syncthreads();
#pragma unroll
        for (int hl = 0; hl < 2; ++hl) {
            int h = w * 2 + hl;
#pragma unroll
            for (int ks = 0; ks < 4; ++ks) {
                bf16x8 bfr = *(const bf16x8*)swz256(vsT, h * 16 + lr, ks * 64 + lg * 16);
#pragma unroll
                for (int mi = 0; mi < 4; ++mi) {
                    bf16x8 a = *(const bf16x8*)&a_n2c[((size_t)(h * 64 + mi * 16 + lr)) * 1024 + n0 + ks * 32 + lg * 8];
                    t1acc[hl][mi] = __builtin_amdgcn_mfma_f32_16x16x32_bf16(a, bfr, t1acc[hl][mi], 0, 0, 0);
                }
            }
        }
    }
    float* op = T1p + (size_t)part * T1SZ;
#pragma unroll
    for (int hl = 0; hl < 2; ++hl) {
        int h = w * 2 + hl;
#pragma unroll
        for (int mi = 0; mi < 4; ++mi)
            *(f32x4*)&op[(((size_t)bt * 8 + h) * 16 + lr) * 64 + mi * 16 + lg * 4] = t1acc[hl][mi];
    }
}

// ---------- T1 partial reduce + bf16 convert ----------
__global__ __launch_bounds__(256) void k_t1conv(const float* __restrict__ T1p,
                                                ushort_t* __restrict__ T1t) {
    size_t i4 = ((size_t)blockIdx.x * 256 + threadIdx.x) * 4;
    float4 s = *(const float4*)&T1p[i4];
#pragma unroll
    for (int p = 1; p < 4; ++p) {
        float4 v = *(const float4*)&T1p[(size_t)p * T1SZ + i4];
        s.x += v.x; s.y += v.y; s.z += v.z; s.w += v.w;
    }
    uint2 o;
    o.x = pk2(s.x, s.y);
    o.y = pk2(s.z, s.w);
    *(uint2*)&T1t[i4] = o;
}

// ---------- fused MFMA FFN: 32-token tiles, mailbox LDS, 6 blocks/CU ----------
// x2mb[set(2)][kk(8)][lane(64)][8] = 16 KB; hmb[kk2(4)][set(2)][lane(64)][8] = 8 KB.
// Wave w: phase A -> token set w>>1, heads (w&1)*4..+3; GEMM1 -> hidden slice w*32
// of each 128-chunk; GEMM2 -> f slice w*32.
__global__ __launch_bounds__(256) void k_ffn(
        const float* __restrict__ input,
        const ushort_t* __restrict__ a_c2nT,
        const ushort_t* __restrict__ T1t,
        const ushort_t* __restrict__ W1f,
        const ushort_t* __restrict__ W2f,
        const float* __restrict__ b1,
        const float* __restrict__ b2,
        float* __restrict__ out,
        float* __restrict__ bn_sum,
        float* __restrict__ bn_sq) {
    __shared__ __align__(16) ushort_t x2mb[2 * 8 * 64 * 8];   // 16 KB
    __shared__ __align__(16) ushort_t hmb[4 * 2 * 64 * 8];    // 8 KB
    int bt = blockIdx.y;
    int n0 = blockIdx.x * 32;
    int t = threadIdx.x;
    int w = t >> 6, lane = t & 63, lr = lane & 15, lg = lane >> 4;
    int rowbase = bt * 1024 + n0;
    int s = w >> 1;            // token set (16 tokens)
    int hbase = (w & 1) * 4;   // 4 heads per wave

    // ---- phase A: vmix MFMA + input load -> mailbox (both x2 halves) ----
    {
        int tokrow = rowbase + s * 16 + lr;
        int slot = ((lg >> 1) * 16 + lr) * 8 + (lg & 1) * 4;  // + 2*(h&1)*128 below
#pragma unroll
        for (int hl = 0; hl < 4; ++hl) {
            int h = hbase + hl;
            const ushort_t* tp = T1t + (((size_t)bt * 8 + h) * 16 + lr) * 64 + lg * 8;
            const ushort_t* ap = a_c2nT + ((size_t)h * 1024 + n0 + s * 16 + lr) * 64 + lg * 8;
            f32x4 vacc = {0.f, 0.f, 0.f, 0.f};
#pragma unroll
            for (int kk = 0; kk < 2; ++kk) {
                bf16x8 af = *(const bf16x8*)(tp + kk * 32);
                bf16x8 bf = *(const bf16x8*)(ap + kk * 32);
                vacc = __builtin_amdgcn_mfma_f32_16x16x32_bf16(af, bf, vacc, 0, 0, 0);
            }
            float4 inp = *(const float4*)&input[(size_t)tokrow * 128 + h * 16 + lg * 4];
            uint2 lft, rgt;
            lft.x = pk2(inp.x - vacc[0], inp.y - vacc[1]);
            lft.y = pk2(inp.z - vacc[2], inp.w - vacc[3]);
            rgt.x = pk2(vacc[0], vacc[1]);
            rgt.y = pk2(vacc[2], vacc[3]);
            int so = slot + (h & 1) * 256;                 // lg_r = 2*(h&1) + (lg>>1)
            *(uint2*)&x2mb[s * 4096 + (h >> 1) * 512 + so]       = lft;  // kk = h>>1
            *(uint2*)&x2mb[s * 4096 + (4 + (h >> 1)) * 512 + so] = rgt;  // kk = 4+(h>>1)
        }
    }
    __syncthreads();

    // ---- y accumulators: token mi*16+lg*4+r, f col w*32+jy*16+lr ----
    f32x4 yacc[2][2];
#pragma unroll
    for (int mi = 0; mi < 2; ++mi)
#pragma unroll
        for (int jy = 0; jy < 2; ++jy) {
            float bb = b2[w * 32 + jy * 16 + lr];
            yacc[mi][jy] = (f32x4){bb, bb, bb, bb};
        }

    for (int ch = 0; ch < 8; ++ch) {
        // prefetch GEMM2 B-fragments (packed, coalesced)
        bf16x8 b2r[4][2];
        {
            const ushort_t* w2p = W2f + (size_t)((ch * 4 + w) * 8) * 512 + lane * 8;
#pragma unroll
            for (int kk = 0; kk < 4; ++kk)
#pragma unroll
                for (int jy = 0; jy < 2; ++jy)
                    b2r[kk][jy] = *(const bf16x8*)(w2p + (kk * 2 + jy) * 512);
        }

        // GEMM1 swapped: hacc[jn][mi]: token mi*16+lr, hidden w*32+jn*16+lg*4+r
        f32x4 hacc[2][2];
#pragma unroll
        for (int jn = 0; jn < 2; ++jn) {
            f32x4 bb = *(const f32x4*)&b1[ch * 128 + w * 32 + jn * 16 + lg * 4];
#pragma unroll
            for (int mi = 0; mi < 2; ++mi) hacc[jn][mi] = bb;
        }
        const ushort_t* w1p = W1f + (size_t)((ch * 4 + w) * 16) * 512 + lane * 8;
        __builtin_amdgcn_s_setprio(1);
#pragma unroll
        for (int kk = 0; kk < 8; ++kk) {
            bf16x8 xf[2];
#pragma unroll
            for (int mi = 0; mi < 2; ++mi)
                xf[mi] = *(const bf16x8*)&x2mb[mi * 4096 + kk * 512 + lane * 8];
#pragma unroll
            for (int jn = 0; jn < 2; ++jn) {
                bf16x8 wf = *(const bf16x8*)(w1p + (kk * 2 + jn) * 512);
#pragma unroll
                for (int mi = 0; mi < 2; ++mi)
                    hacc[jn][mi] = __builtin_amdgcn_mfma_f32_16x16x32_bf16(wf, xf[mi], hacc[jn][mi], 0, 0, 0);
            }
        }
        __builtin_amdgcn_s_setprio(0);
        __syncthreads();   // prev chunk's GEMM2 hmb reads complete
        // GELU -> hmb mailbox: wave w owns kk2=w; lg_r = jn*2+(lg>>1), e=(lg&1)*4+r
#pragma unroll
        for (int jn = 0; jn < 2; ++jn)
#pragma unroll
            for (int mi = 0; mi < 2; ++mi) {
                uint2 o;
                o.x = pk2(gelu_f(hacc[jn][mi][0]), gelu_f(hacc[jn][mi][1]));
                o.y = pk2(gelu_f(hacc[jn][mi][2]), gelu_f(hacc[jn][mi][3]));
                *(uint2*)&hmb[w * 1024 + mi * 512 +
                              ((jn * 2 + (lg >> 1)) * 16 + lr) * 8 + (lg & 1) * 4] = o;
            }
        __syncthreads();   // hmb visible
        // GEMM2 standard
        __builtin_amdgcn_s_setprio(1);
#pragma unroll
        for (int kk = 0; kk < 4; ++kk) {
            bf16x8 a4[2];
#pragma unroll
            for (int mi = 0; mi < 2; ++mi)
                a4[mi] = *(const bf16x8*)&hmb[kk * 1024 + mi * 512 + lane * 8];
#pragma unroll
            for (int jy = 0; jy < 2; ++jy)
#pragma unroll
                for (int mi = 0; mi < 2; ++mi)
                    yacc[mi][jy] = __builtin_amdgcn_mfma_f32_16x16x32_bf16(a4[mi], b2r[kk][jy], yacc[mi][jy], 0, 0, 0);
        }
        __builtin_amdgcn_s_setprio(0);
    }

    // ---- epilogue: residual + store + BN partials ----
    float sacc[2] = {0.f, 0.f}, qacc[2] = {0.f, 0.f};
#pragma unroll
    for (int mi = 0; mi < 2; ++mi)
#pragma unroll
        for (int jy = 0; jy < 2; ++jy)
#pragma unroll
            for (int r = 0; r < 4; ++r) {
                int gr = rowbase + mi * 16 + lg * 4 + r;
                int gc = w * 32 + jy * 16 + lr;
                float val = yacc[mi][jy][r] + input[(size_t)gr * 128 + gc];
                out[(size_t)gr * 128 + gc] = val;
                sacc[jy] += val;
                qacc[jy] += val * val;
            }
#pragma unroll
    for (int jy = 0; jy < 2; ++jy) {
        float s2 = sacc[jy], q2 = qacc[jy];
        s2 += __shfl_xor(s2, 16); s2 += __shfl_xor(s2, 32);
        q2 += __shfl_xor(q2, 16); q2 += __shfl_xor(q2, 32);
        if (lg == 0) {
            atomicAdd(&bn_sum[w * 32 + jy * 16 + lr], s2);
            atomicAdd(&bn_sq[w * 32 + jy * 16 + lr], q2);
        }
    }
}

// ---------- BN finalize ----------
__global__ void k_bnfin(const float* __restrict__ bn_sum, const float* __restrict__ bn_sq,
                        const float* __restrict__ gamma, const float* __restrict__ beta,
                        float* __restrict__ scale, float* __restrict__ shift) {
    int f = threadIdx.x;
    float mean = bn_sum[f] * (1.0f / CNT);
    float var  = bn_sq[f]  * (1.0f / CNT) - mean * mean;
    float sc = gamma[f] * rsqrtf(var + 1e-5f);
    scale[f] = sc;
    shift[f] = beta[f] - mean * sc;
}

// ---------- BN apply (in place) ----------
__global__ __launch_bounds__(256) void k_bnapply(float* __restrict__ out,
                                                 const float* __restrict__ scale,
                                                 const float* __restrict__ shift) {
    size_t idx = (size_t)blockIdx.x * 256 + threadIdx.x;
    int c = (int)((idx * 4) & 127);
    float4 v = *(float4*)&out[idx * 4];
    float4 sc = *(const float4*)&scale[c];
    float4 sh = *(const float4*)&shift[c];
    v.x = fmaf(v.x, sc.x, sh.x);
    v.y = fmaf(v.y, sc.y, sh.y);
    v.z = fmaf(v.z, sc.z, sh.z);
    v.w = fmaf(v.w, sc.w, sh.w);
    *(float4*)&out[idx * 4] = v;
}

extern "C" void kernel_launch(void* const* d_in, const int* in_sizes, int n_in,
                              void* d_out, int out_size, void* d_ws, size_t ws_size,
                              hipStream_t stream) {
    const float* input    = (const float*)d_in[0];
    const float* Wv       = (const float*)d_in[1];
    const float* bv       = (const float*)d_in[2];
    const float* adaptive = (const float*)d_in[3];
    const float* cores    = (const float*)d_in[4];
    const float* W1       = (const float*)d_in[5];
    const float* b1       = (const float*)d_in[6];
    const float* W2       = (const float*)d_in[7];
    const float* b2       = (const float*)d_in[8];
    const float* gamma    = (const float*)d_in[9];
    const float* beta     = (const float*)d_in[10];
    float* out = (float*)d_out;
    float* ws  = (float*)d_ws;

    float*    aff    = ws;                           // 524288 f
    ushort_t* a_n2c  = (ushort_t*)(ws + 524288);     // 524288 us
    ushort_t* a_c2nT = (ushort_t*)(ws + 786432);     // 524288 us
    ushort_t* T1t    = (ushort_t*)(ws + 1048576);    // 1572864 us
    ushort_t* W1f    = (ushort_t*)(ws + 1835008);    // 262144 us
    ushort_t* W2f    = (ushort_t*)(ws + 1966080);    // 131072 us
    ushort_t* WvT    = (ushort_t*)(ws + 2031616);    // 16384 us
    float* bn_sum    = ws + 2039808;
    float* bn_sq     = bn_sum + 128;
    float* scale     = bn_sum + 256;
    float* shift     = bn_sum + 384;
    float* T1p       = ws + 2097152;                 // 4 x T1SZ f

    k_aff    <<<2048, 256, 0, stream>>>(cores, adaptive, aff);
    k_sm_n   <<<512, 256, 0, stream>>>(aff, a_n2c);
    k_sm_c   <<<128, 256, 0, stream>>>(aff, a_c2nT);
    k_wprep_v<<<4, 256, 0, stream>>>(Wv, WvT);
    k_wpack1 <<<128, 256, 0, stream>>>(W1, W1f);
    k_wpack2 <<<64, 256, 0, stream>>>(W2, W2f);
    k_vs1    <<<dim3(BT, 4), 256, 0, stream>>>(input, WvT, bv, a_n2c, T1p);
    k_t1conv <<<1536, 256, 0, stream>>>(T1p, T1t);
    hipMemsetAsync(bn_sum, 0, 256 * sizeof(float), stream);
    k_ffn    <<<dim3(32, BT), 256, 0, stream>>>(input, a_c2nT, T1t, W1f, W2f,
                                                b1, b2, out, bn_sum, bn_sq);
    k_bnfin  <<<1, 128, 0, stream>>>(bn_sum, bn_sq, gamma, beta, scale, shift);
    k_bnapply<<<(out_size / 4) / 256, 256, 0, stream>>>(out, scale, shift);
}

// Round 15
// 410.156 us; speedup vs baseline: 1.0230x; 1.0230x over previous
//
#include <hip/hip_runtime.h>
#include <math.h>

// Problem constants
#define BB 16
#define TT 12
#define NN 1024
#define FF 128
#define BT 192
#define BTN 196608
#define CNT ((float)BTN)
#define T1SZ 1572864   // BT*8*16*64 elements

typedef unsigned short ushort_t;
typedef __attribute__((ext_vector_type(8))) short bf16x8;
typedef __attribute__((ext_vector_type(4))) float f32x4;

__device__ __forceinline__ ushort_t f2bf(float x) {
    union { float f; unsigned u; } c; c.f = x;
    unsigned r = c.u + 0x7fffu + ((c.u >> 16) & 1u);
    return (ushort_t)(r >> 16);
}
__device__ __forceinline__ float bf2f(ushort_t u) {
    union { unsigned u32; float f; } c; c.u32 = ((unsigned)u) << 16; return c.f;
}
// packed f32x2 -> bf16x2 via native v_cvt_pk_bf16_f32 (RNE), 1 VALU op.
__device__ __forceinline__ unsigned pk2(float a, float b) {
    unsigned r;
    asm("v_cvt_pk_bf16_f32 %0, %1, %2" : "=v"(r) : "v"(a), "v"(b));
    return r;
}
// tanh-form GELU
__device__ __forceinline__ float gelu_f(float x) {
    float u = x * x;
    float s = x * fmaf(u, -0.10294428f, -2.30220852f);
    float e = __builtin_amdgcn_exp2f(s);
    return x * __builtin_amdgcn_rcpf(1.0f + e);
}

// XOR-swizzle helper (k_vs1 only)
__device__ __forceinline__ char* swz256(void* base, int row, int byteoff) {
    return (char*)base + row * 256 + (byteoff ^ ((row & 7) << 4));
}

// ---------- aff[h,c,n] ----------
__global__ __launch_bounds__(256) void k_aff(const float* __restrict__ cores,
                                             const float* __restrict__ adaptive,
                                             float* __restrict__ aff) {
    int idx = blockIdx.x * 256 + threadIdx.x;
    int n  = idx & 1023;
    int hc = idx >> 10;
    int h  = hc >> 6;
    const float* cp = cores + hc * 16;
    const float* ap = adaptive + h * 16384 + n;
    float s = 0.f;
#pragma unroll
    for (int d = 0; d < 16; ++d) s = fmaf(cp[d], ap[d * 1024], s);
    aff[idx] = s * 0.25f;
}

// ---------- softmax over n -> bf16 a_n2c[h,c,n] ----------
__global__ __launch_bounds__(256) void k_sm_n(const float* __restrict__ aff,
                                              ushort_t* __restrict__ out) {
    int row = blockIdx.x;
    const float* p = aff + row * 1024;
    int t = threadIdx.x;
    __shared__ float red[8];
    float v0 = p[t], v1 = p[t + 256], v2 = p[t + 512], v3 = p[t + 768];
    float m = fmaxf(fmaxf(v0, v1), fmaxf(v2, v3));
#pragma unroll
    for (int off = 32; off >= 1; off >>= 1) m = fmaxf(m, __shfl_xor(m, off));
    if ((t & 63) == 0) red[t >> 6] = m;
    __syncthreads();
    m = fmaxf(fmaxf(red[0], red[1]), fmaxf(red[2], red[3]));
    v0 = expf(v0 - m); v1 = expf(v1 - m); v2 = expf(v2 - m); v3 = expf(v3 - m);
    float s = v0 + v1 + v2 + v3;
#pragma unroll
    for (int off = 32; off >= 1; off >>= 1) s += __shfl_xor(s, off);
    __syncthreads();
    if ((t & 63) == 0) red[4 + (t >> 6)] = s;
    __syncthreads();
    s = red[4] + red[5] + red[6] + red[7];
    float inv = 1.0f / s;
    out[row * 1024 + t]       = f2bf(v0 * inv);
    out[row * 1024 + t + 256] = f2bf(v1 * inv);
    out[row * 1024 + t + 512] = f2bf(v2 * inv);
    out[row * 1024 + t + 768] = f2bf(v3 * inv);
}

// ---------- softmax over c -> transposed bf16 a_c2nT[h][n][c] ----------
__global__ __launch_bounds__(256) void k_sm_c(const float* __restrict__ aff,
                                              ushort_t* __restrict__ a_c2nT) {
    __shared__ ushort_t tile[64][72];
    int b = blockIdx.x;
    int h = b >> 4, n0 = (b & 15) * 64;
    int t = threadIdx.x;
    int nl = t >> 2, q = t & 3;
    const float* p = aff + h * 65536 + n0 + nl;
    float v[16];
    float m = -1e30f;
#pragma unroll
    for (int i = 0; i < 16; ++i) {
        v[i] = p[(q * 16 + i) * 1024];
        m = fmaxf(m, v[i]);
    }
    m = fmaxf(m, __shfl_xor(m, 1));
    m = fmaxf(m, __shfl_xor(m, 2));
    float s = 0.f;
#pragma unroll
    for (int i = 0; i < 16; ++i) { v[i] = expf(v[i] - m); s += v[i]; }
    s += __shfl_xor(s, 1);
    s += __shfl_xor(s, 2);
    float inv = 1.0f / s;
#pragma unroll
    for (int i = 0; i < 16; ++i) tile[nl][q * 16 + i] = f2bf(v[i] * inv);
    __syncthreads();
    ushort_t* ob = a_c2nT + ((size_t)h * 1024 + n0) * 64;
    for (int i = t; i < 512; i += 256) {
        int r = i >> 3, cq = i & 7;
        *(bf16x8*)&ob[r * 64 + cq * 8] = *(bf16x8*)&tile[r][cq * 8];
    }
}

// ---------- Wv transpose -> bf16 WvT[128][128] ----------
__global__ __launch_bounds__(256) void k_wprep_v(const float* __restrict__ Wv,
                                                 ushort_t* __restrict__ WvT) {
    __shared__ float tile[64][65];
    int b = blockIdx.x;
    int r0 = (b >> 1) * 64, c0 = (b & 1) * 64;
    int t = threadIdx.x;
    for (int i = t; i < 4096; i += 256) {
        int r = i >> 6, c = i & 63;
        tile[r][c] = Wv[(size_t)(r0 + r) * 128 + c0 + c];
    }
    __syncthreads();
    for (int i = t; i < 4096; i += 256) {
        int c = i >> 6, r = i & 63;
        WvT[(size_t)(c0 + c) * 128 + r0 + r] = f2bf(tile[r][c]);
    }
}

// ---------- W1 fragment-pack: W1f[ch][w][kk][jn][lane]*8 ----------
__global__ __launch_bounds__(256) void k_wpack1(const float* __restrict__ W1,
                                                ushort_t* __restrict__ W1f) {
    int tid = blockIdx.x * 256 + threadIdx.x;   // < 32768
    int lane = tid & 63, jn = (tid >> 6) & 1, kk = (tid >> 7) & 7;
    int w = (tid >> 10) & 3, ch = tid >> 12;
    int lr = lane & 15, lg = lane >> 4;
    int n = ch * 128 + w * 32 + jn * 16 + lr;
    int kb = kk * 32 + lg * 8;
    ushort_t o[8];
#pragma unroll
    for (int e = 0; e < 8; ++e) o[e] = f2bf(W1[(size_t)(kb + e) * 1024 + n]);
    *(bf16x8*)&W1f[(size_t)tid * 8] = *(bf16x8*)o;
}

// ---------- W2 fragment-pack: W2f[ch][w][kk][jy][lane]*8 ----------
__global__ __launch_bounds__(256) void k_wpack2(const float* __restrict__ W2,
                                                ushort_t* __restrict__ W2f) {
    int tid = blockIdx.x * 256 + threadIdx.x;   // < 16384
    int lane = tid & 63, jy = (tid >> 6) & 1, kk = (tid >> 7) & 3;
    int w = (tid >> 9) & 3, ch = tid >> 11;
    int lr = lane & 15, lg = lane >> 4;
    int f = w * 32 + jy * 16 + lr;
    int kb = ch * 128 + kk * 32 + lg * 8;
    ushort_t o[8];
#pragma unroll
    for (int e = 0; e < 8; ++e) o[e] = f2bf(W2[(size_t)(kb + e) * 128 + f]);
    *(bf16x8*)&W2f[(size_t)tid * 8] = *(bf16x8*)o;
}

// ---------- fused v-proj + stage1, 4-way n-split ----------
__global__ __launch_bounds__(256) void k_vs1(const float* __restrict__ input,
                                             const ushort_t* __restrict__ WvT,
                                             const float* __restrict__ bv,
                                             const ushort_t* __restrict__ a_n2c,
                                             float* __restrict__ T1p) {
    __shared__ __align__(16) ushort_t as_lds[128 * 128];
    __shared__ __align__(16) ushort_t vsT[128 * 128];
    int bt = blockIdx.x;
    int part = blockIdx.y;
    int t = threadIdx.x, w = t >> 6, lane = t & 63, lr = lane & 15, lg = lane >> 4;

    f32x4 t1acc[2][4];
#pragma unroll
    for (int hl = 0; hl < 2; ++hl)
#pragma unroll
        for (int mi = 0; mi < 4; ++mi) t1acc[hl][mi] = (f32x4){0.f, 0.f, 0.f, 0.f};

    for (int c8 = part * 2; c8 < part * 2 + 2; ++c8) {
        int n0 = c8 * 128;
        __syncthreads();
        for (int j = 0; j < 16; ++j) {
            int i = j * 256 + t;
            int r = i >> 5, cq = i & 31;
            float4 f = *(const float4*)&input[((size_t)(bt * 1024 + n0 + r)) * 128 + cq * 4];
            uint2 o;
            o.x = pk2(f.x, f.y);
            o.y = pk2(f.z, f.w);
            *(uint2*)swz256(as_lds, r, cq * 8) = o;
        }
        __syncthreads();
        f32x4 vacc[2][8];
#pragma unroll
        for (int mi = 0; mi < 2; ++mi)
#pragma unroll
            for (int jn = 0; jn < 8; ++jn) {
                float bb = bv[jn * 16 + lr];
                vacc[mi][jn] = (f32x4){bb, bb, bb, bb};
            }
#pragma unroll
        for (int ks = 0; ks < 4; ++ks) {
            bf16x8 a[2];
#pragma unroll
            for (int mi = 0; mi < 2; ++mi)
                a[mi] = *(const bf16x8*)swz256(as_lds, w * 32 + mi * 16 + lr, ks * 64 + lg * 16);
#pragma unroll
            for (int jn = 0; jn < 8; ++jn) {
                bf16x8 bfr = *(const bf16x8*)&WvT[(size_t)(jn * 16 + lr) * 128 + ks * 32 + lg * 8];
#pragma unroll
                for (int mi = 0; mi < 2; ++mi)
                    vacc[mi][jn] = __builtin_amdgcn_mfma_f32_16x16x32_bf16(a[mi], bfr, vacc[mi][jn], 0, 0, 0);
            }
        }
#pragma unroll
        for (int mi = 0; mi < 2; ++mi)
#pragma unroll
            for (int jn = 0; jn < 8; ++jn) {
                uint2 o;
                o.x = pk2(vacc[mi][jn][0], vacc[mi][jn][1]);
                o.y = pk2(vacc[mi][jn][2], vacc[mi][jn][3]);
                *(uint2*)swz256(vsT, jn * 16 + lr, w * 64 + mi * 32 + lg * 8) = o;
            }
        __syncthreads();
#pragma unroll
        for (int hl = 0; hl < 2; ++hl) {
            int h = w * 2 + hl;
#pragma unroll
            for (int ks = 0; ks < 4; ++ks) {
                bf16x8 bfr = *(const bf16x8*)swz256(vsT, h * 16 + lr, ks * 64 + lg * 16);
#pragma unroll
                for (int mi = 0; mi < 4; ++mi) {
                    bf16x8 a = *(const bf16x8*)&a_n2c[((size_t)(h * 64 + mi * 16 + lr)) * 1024 + n0 + ks * 32 + lg * 8];
                    t1acc[hl][mi] = __builtin_amdgcn_mfma_f32_16x16x32_bf16(a, bfr, t1acc[hl][mi], 0, 0, 0);
                }
            }
        }
    }
    float* op = T1p + (size_t)part * T1SZ;
#pragma unroll
    for (int hl = 0; hl < 2; ++hl) {
        int h = w * 2 + hl;
#pragma unroll
        for (int mi = 0; mi < 4; ++mi)
            *(f32x4*)&op[(((size_t)bt * 8 + h) * 16 + lr) * 64 + mi * 16 + lg * 4] = t1acc[hl][mi];
    }
}

// ---------- T1 partial reduce + bf16 convert ----------
__global__ __launch_bounds__(256) void k_t1conv(const float* __restrict__ T1p,
                                                ushort_t* __restrict__ T1t) {
    size_t i4 = ((size_t)blockIdx.x * 256 + threadIdx.x) * 4;
    float4 s = *(const float4*)&T1p[i4];
#pragma unroll
    for (int p = 1; p < 4; ++p) {
        float4 v = *(const float4*)&T1p[(size_t)p * T1SZ + i4];
        s.x += v.x; s.y += v.y; s.z += v.z; s.w += v.w;
    }
    uint2 o;
    o.x = pk2(s.x, s.y);
    o.y = pk2(s.z, s.w);
    *(uint2*)&T1t[i4] = o;
}

// ---------- fused MFMA FFN: 32-token tiles, DOUBLE-BUFFERED hmb (9 barriers) ----------
// x2mb[set(2)][kk(8)][lane(64)][8] = 16 KB; hmb[2][kk2(4)][set(2)][lane(64)][8] = 16 KB.
// One barrier per chunk: GELU writes hmb[ch&1]; bar; GEMM2 reads hmb[ch&1].
// Chunk ch+2's writes to the same buffer are fenced by bar(ch+1): every wave
// reaches bar(ch+1) only after its own GEMM2 read of chunk ch (program order).
__global__ __launch_bounds__(256) void k_ffn(
        const float* __restrict__ input,
        const ushort_t* __restrict__ a_c2nT,
        const ushort_t* __restrict__ T1t,
        const ushort_t* __restrict__ W1f,
        const ushort_t* __restrict__ W2f,
        const float* __restrict__ b1,
        const float* __restrict__ b2,
        float* __restrict__ out,
        float* __restrict__ bn_sum,
        float* __restrict__ bn_sq) {
    __shared__ __align__(16) ushort_t x2mb[2 * 8 * 64 * 8];      // 16 KB
    __shared__ __align__(16) ushort_t hmb[2][4 * 2 * 64 * 8];    // 2 x 8 KB
    int bt = blockIdx.y;
    int n0 = blockIdx.x * 32;
    int t = threadIdx.x;
    int w = t >> 6, lane = t & 63, lr = lane & 15, lg = lane >> 4;
    int rowbase = bt * 1024 + n0;
    int s = w >> 1;            // token set (16 tokens)
    int hbase = (w & 1) * 4;   // 4 heads per wave

    // ---- phase A: vmix MFMA + input load -> mailbox (both x2 halves) ----
    {
        int tokrow = rowbase + s * 16 + lr;
        int slot = ((lg >> 1) * 16 + lr) * 8 + (lg & 1) * 4;
#pragma unroll
        for (int hl = 0; hl < 4; ++hl) {
            int h = hbase + hl;
            const ushort_t* tp = T1t + (((size_t)bt * 8 + h) * 16 + lr) * 64 + lg * 8;
            const ushort_t* ap = a_c2nT + ((size_t)h * 1024 + n0 + s * 16 + lr) * 64 + lg * 8;
            f32x4 vacc = {0.f, 0.f, 0.f, 0.f};
#pragma unroll
            for (int kk = 0; kk < 2; ++kk) {
                bf16x8 af = *(const bf16x8*)(tp + kk * 32);
                bf16x8 bf = *(const bf16x8*)(ap + kk * 32);
                vacc = __builtin_amdgcn_mfma_f32_16x16x32_bf16(af, bf, vacc, 0, 0, 0);
            }
            float4 inp = *(const float4*)&input[(size_t)tokrow * 128 + h * 16 + lg * 4];
            uint2 lft, rgt;
            lft.x = pk2(inp.x - vacc[0], inp.y - vacc[1]);
            lft.y = pk2(inp.z - vacc[2], inp.w - vacc[3]);
            rgt.x = pk2(vacc[0], vacc[1]);
            rgt.y = pk2(vacc[2], vacc[3]);
            int so = slot + (h & 1) * 256;
            *(uint2*)&x2mb[s * 4096 + (h >> 1) * 512 + so]       = lft;
            *(uint2*)&x2mb[s * 4096 + (4 + (h >> 1)) * 512 + so] = rgt;
        }
    }
    __syncthreads();

    // ---- y accumulators: token mi*16+lg*4+r, f col w*32+jy*16+lr ----
    f32x4 yacc[2][2];
#pragma unroll
    for (int mi = 0; mi < 2; ++mi)
#pragma unroll
        for (int jy = 0; jy < 2; ++jy) {
            float bb = b2[w * 32 + jy * 16 + lr];
            yacc[mi][jy] = (f32x4){bb, bb, bb, bb};
        }

    for (int ch = 0; ch < 8; ++ch) {
        ushort_t* hbuf = hmb[ch & 1];
        // prefetch GEMM2 B-fragments (packed, coalesced)
        bf16x8 b2r[4][2];
        {
            const ushort_t* w2p = W2f + (size_t)((ch * 4 + w) * 8) * 512 + lane * 8;
#pragma unroll
            for (int kk = 0; kk < 4; ++kk)
#pragma unroll
                for (int jy = 0; jy < 2; ++jy)
                    b2r[kk][jy] = *(const bf16x8*)(w2p + (kk * 2 + jy) * 512);
        }

        // GEMM1 swapped: hacc[jn][mi]: token mi*16+lr, hidden w*32+jn*16+lg*4+r
        f32x4 hacc[2][2];
#pragma unroll
        for (int jn = 0; jn < 2; ++jn) {
            f32x4 bb = *(const f32x4*)&b1[ch * 128 + w * 32 + jn * 16 + lg * 4];
#pragma unroll
            for (int mi = 0; mi < 2; ++mi) hacc[jn][mi] = bb;
        }
        const ushort_t* w1p = W1f + (size_t)((ch * 4 + w) * 16) * 512 + lane * 8;
        __builtin_amdgcn_s_setprio(1);
#pragma unroll
        for (int kk = 0; kk < 8; ++kk) {
            bf16x8 xf[2];
#pragma unroll
            for (int mi = 0; mi < 2; ++mi)
                xf[mi] = *(const bf16x8*)&x2mb[mi * 4096 + kk * 512 + lane * 8];
#pragma unroll
            for (int jn = 0; jn < 2; ++jn) {
                bf16x8 wf = *(const bf16x8*)(w1p + (kk * 2 + jn) * 512);
#pragma unroll
                for (int mi = 0; mi < 2; ++mi)
                    hacc[jn][mi] = __builtin_amdgcn_mfma_f32_16x16x32_bf16(wf, xf[mi], hacc[jn][mi], 0, 0, 0);
            }
        }
        __builtin_amdgcn_s_setprio(0);
        // GELU -> hmb[ch&1]: lg_r = jn*2+(lg>>1), e=(lg&1)*4+r
#pragma unroll
        for (int jn = 0; jn < 2; ++jn)
#pragma unroll
            for (int mi = 0; mi < 2; ++mi) {
                uint2 o;
                o.x = pk2(gelu_f(hacc[jn][mi][0]), gelu_f(hacc[jn][mi][1]));
                o.y = pk2(gelu_f(hacc[jn][mi][2]), gelu_f(hacc[jn][mi][3]));
                *(uint2*)&hbuf[w * 1024 + mi * 512 +
                               ((jn * 2 + (lg >> 1)) * 16 + lr) * 8 + (lg & 1) * 4] = o;
            }
        __syncthreads();   // hmb[ch&1] visible; also fences reuse (see header)
        // GEMM2 standard
        __builtin_amdgcn_s_setprio(1);
#pragma unroll
        for (int kk = 0; kk < 4; ++kk) {
            bf16x8 a4[2];
#pragma unroll
            for (int mi = 0; mi < 2; ++mi)
                a4[mi] = *(const bf16x8*)&hbuf[kk * 1024 + mi * 512 + lane * 8];
#pragma unroll
            for (int jy = 0; jy < 2; ++jy)
#pragma unroll
                for (int mi = 0; mi < 2; ++mi)
                    yacc[mi][jy] = __builtin_amdgcn_mfma_f32_16x16x32_bf16(a4[mi], b2r[kk][jy], yacc[mi][jy], 0, 0, 0);
        }
        __builtin_amdgcn_s_setprio(0);
    }

    // ---- epilogue: residual + store + BN partials ----
    float sacc[2] = {0.f, 0.f}, qacc[2] = {0.f, 0.f};
#pragma unroll
    for (int mi = 0; mi < 2; ++mi)
#pragma unroll
        for (int jy = 0; jy < 2; ++jy)
#pragma unroll
            for (int r = 0; r < 4; ++r) {
                int gr = rowbase + mi * 16 + lg * 4 + r;
                int gc = w * 32 + jy * 16 + lr;
                float val = yacc[mi][jy][r] + input[(size_t)gr * 128 + gc];
                out[(size_t)gr * 128 + gc] = val;
                sacc[jy] += val;
                qacc[jy] += val * val;
            }
#pragma unroll
    for (int jy = 0; jy < 2; ++jy) {
        float s2 = sacc[jy], q2 = qacc[jy];
        s2 += __shfl_xor(s2, 16); s2 += __shfl_xor(s2, 32);
        q2 += __shfl_xor(q2, 16); q2 += __shfl_xor(q2, 32);
        if (lg == 0) {
            atomicAdd(&bn_sum[w * 32 + jy * 16 + lr], s2);
            atomicAdd(&bn_sq[w * 32 + jy * 16 + lr], q2);
        }
    }
}

// ---------- BN finalize ----------
__global__ void k_bnfin(const float* __restrict__ bn_sum, const float* __restrict__ bn_sq,
                        const float* __restrict__ gamma, const float* __restrict__ beta,
                        float* __restrict__ scale, float* __restrict__ shift) {
    int f = threadIdx.x;
    float mean = bn_sum[f] * (1.0f / CNT);
    float var  = bn_sq[f]  * (1.0f / CNT) - mean * mean;
    float sc = gamma[f] * rsqrtf(var + 1e-5f);
    scale[f] = sc;
    shift[f] = beta[f] - mean * sc;
}

// ---------- BN apply (in place) ----------
__global__ __launch_bounds__(256) void k_bnapply(float* __restrict__ out,
                                                 const float* __restrict__ scale,
                                                 const float* __restrict__ shift) {
    size_t idx = (size_t)blockIdx.x * 256 + threadIdx.x;
    int c = (int)((idx * 4) & 127);
    float4 v = *(float4*)&out[idx * 4];
    float4 sc = *(const float4*)&scale[c];
    float4 sh = *(const float4*)&shift[c];
    v.x = fmaf(v.x, sc.x, sh.x);
    v.y = fmaf(v.y, sc.y, sh.y);
    v.z = fmaf(v.z, sc.z, sh.z);
    v.w = fmaf(v.w, sc.w, sh.w);
    *(float4*)&out[idx * 4] = v;
}

extern "C" void kernel_launch(void* const* d_in, const int* in_sizes, int n_in,
                              void* d_out, int out_size, void* d_ws, size_t ws_size,
                              hipStream_t stream) {
    const float* input    = (const float*)d_in[0];
    const float* Wv       = (const float*)d_in[1];
    const float* bv       = (const float*)d_in[2];
    const float* adaptive = (const float*)d_in[3];
    const float* cores    = (const float*)d_in[4];
    const float* W1       = (const float*)d_in[5];
    const float* b1       = (const float*)d_in[6];
    const float* W2       = (const float*)d_in[7];
    const float* b2       = (const float*)d_in[8];
    const float* gamma    = (const float*)d_in[9];
    const float* beta     = (const float*)d_in[10];
    float* out = (float*)d_out;
    float* ws  = (float*)d_ws;

    float*    aff    = ws;                           // 524288 f
    ushort_t* a_n2c  = (ushort_t*)(ws + 524288);     // 524288 us
    ushort_t* a_c2nT = (ushort_t*)(ws + 786432);     // 524288 us
    ushort_t* T1t    = (ushort_t*)(ws + 1048576);    // 1572864 us
    ushort_t* W1f    = (ushort_t*)(ws + 1835008);    // 262144 us
    ushort_t* W2f    = (ushort_t*)(ws + 1966080);    // 131072 us
    ushort_t* WvT    = (ushort_t*)(ws + 2031616);    // 16384 us
    float* bn_sum    = ws + 2039808;
    float* bn_sq     = bn_sum + 128;
    float* scale     = bn_sum + 256;
    float* shift     = bn_sum + 384;
    float* T1p       = ws + 2097152;                 // 4 x T1SZ f

    k_aff    <<<2048, 256, 0, stream>>>(cores, adaptive, aff);
    k_sm_n   <<<512, 256, 0, stream>>>(aff, a_n2c);
    k_sm_c   <<<128, 256, 0, stream>>>(aff, a_c2nT);
    k_wprep_v<<<4, 256, 0, stream>>>(Wv, WvT);
    k_wpack1 <<<128, 256, 0, stream>>>(W1, W1f);
    k_wpack2 <<<64, 256, 0, stream>>>(W2, W2f);
    k_vs1    <<<dim3(BT, 4), 256, 0, stream>>>(input, WvT, bv, a_n2c, T1p);
    k_t1conv <<<1536, 256, 0, stream>>>(T1p, T1t);
    hipMemsetAsync(bn_sum, 0, 256 * sizeof(float), stream);
    k_ffn    <<<dim3(32, BT), 256, 0, stream>>>(input, a_c2nT, T1t, W1f, W2f,
                                                b1, b2, out, bn_sum, bn_sq);
    k_bnfin  <<<1, 128, 0, stream>>>(bn_sum, bn_sq, gamma, beta, scale, shift);
    k_bnapply<<<(out_size / 4) / 256, 256, 0, stream>>>(out, scale, shift);
}

// Round 16
// 402.275 us; speedup vs baseline: 1.0430x; 1.0196x over previous
//
#include <hip/hip_runtime.h>
#include <math.h>

// Problem constants
#define BB 16
#define TT 12
#define NN 1024
#define FF 128
#define BT 192
#define BTN 196608
#define CNT ((float)BTN)
#define T1SZ 1572864   // BT*8*16*64 elements

typedef unsigned short ushort_t;
typedef __attribute__((ext_vector_type(8))) short bf16x8;
typedef __attribute__((ext_vector_type(4))) float f32x4;

__device__ __forceinline__ ushort_t f2bf(float x) {
    union { float f; unsigned u; } c; c.f = x;
    unsigned r = c.u + 0x7fffu + ((c.u >> 16) & 1u);
    return (ushort_t)(r >> 16);
}
__device__ __forceinline__ float bf2f(ushort_t u) {
    union { unsigned u32; float f; } c; c.u32 = ((unsigned)u) << 16; return c.f;
}
// packed f32x2 -> bf16x2 via native v_cvt_pk_bf16_f32 (RNE), 1 VALU op.
__device__ __forceinline__ unsigned pk2(float a, float b) {
    unsigned r;
    asm("v_cvt_pk_bf16_f32 %0, %1, %2" : "=v"(r) : "v"(a), "v"(b));
    return r;
}
// tanh-form GELU
__device__ __forceinline__ float gelu_f(float x) {
    float u = x * x;
    float s = x * fmaf(u, -0.10294428f, -2.30220852f);
    float e = __builtin_amdgcn_exp2f(s);
    return x * __builtin_amdgcn_rcpf(1.0f + e);
}

// XOR-swizzle helper (k_vs1 only)
__device__ __forceinline__ char* swz256(void* base, int row, int byteoff) {
    return (char*)base + row * 256 + (byteoff ^ ((row & 7) << 4));
}

// ---------- fused aff + softmax over n -> bf16 a_n2c[h,c,n]; also writes aff ----------
// Block = one (h,c) row. aff computed inline (cores row is uniform, adaptive
// reads coalesced over n); written out for k_sm_c's column softmax.
__global__ __launch_bounds__(256) void k_sm_n(const float* __restrict__ cores,
                                              const float* __restrict__ adaptive,
                                              float* __restrict__ aff,
                                              ushort_t* __restrict__ out) {
    int row = blockIdx.x;                 // h*64+c
    int h = row >> 6;
    int t = threadIdx.x;
    __shared__ float red[8];
    const float* cp = cores + row * 16;
    const float* ap = adaptive + h * 16384;
    float v0 = 0.f, v1 = 0.f, v2 = 0.f, v3 = 0.f;
#pragma unroll
    for (int d = 0; d < 16; ++d) {
        float c = cp[d];
        const float* an = ap + d * 1024;
        v0 = fmaf(c, an[t], v0);
        v1 = fmaf(c, an[t + 256], v1);
        v2 = fmaf(c, an[t + 512], v2);
        v3 = fmaf(c, an[t + 768], v3);
    }
    v0 *= 0.25f; v1 *= 0.25f; v2 *= 0.25f; v3 *= 0.25f;
    aff[row * 1024 + t]       = v0;
    aff[row * 1024 + t + 256] = v1;
    aff[row * 1024 + t + 512] = v2;
    aff[row * 1024 + t + 768] = v3;
    float m = fmaxf(fmaxf(v0, v1), fmaxf(v2, v3));
#pragma unroll
    for (int off = 32; off >= 1; off >>= 1) m = fmaxf(m, __shfl_xor(m, off));
    if ((t & 63) == 0) red[t >> 6] = m;
    __syncthreads();
    m = fmaxf(fmaxf(red[0], red[1]), fmaxf(red[2], red[3]));
    v0 = expf(v0 - m); v1 = expf(v1 - m); v2 = expf(v2 - m); v3 = expf(v3 - m);
    float s = v0 + v1 + v2 + v3;
#pragma unroll
    for (int off = 32; off >= 1; off >>= 1) s += __shfl_xor(s, off);
    __syncthreads();
    if ((t & 63) == 0) red[4 + (t >> 6)] = s;
    __syncthreads();
    s = red[4] + red[5] + red[6] + red[7];
    float inv = 1.0f / s;
    out[row * 1024 + t]       = f2bf(v0 * inv);
    out[row * 1024 + t + 256] = f2bf(v1 * inv);
    out[row * 1024 + t + 512] = f2bf(v2 * inv);
    out[row * 1024 + t + 768] = f2bf(v3 * inv);
}

// ---------- softmax over c -> transposed bf16 a_c2nT[h][n][c] ----------
__global__ __launch_bounds__(256) void k_sm_c(const float* __restrict__ aff,
                                              ushort_t* __restrict__ a_c2nT) {
    __shared__ ushort_t tile[64][72];
    int b = blockIdx.x;
    int h = b >> 4, n0 = (b & 15) * 64;
    int t = threadIdx.x;
    int nl = t >> 2, q = t & 3;
    const float* p = aff + h * 65536 + n0 + nl;
    float v[16];
    float m = -1e30f;
#pragma unroll
    for (int i = 0; i < 16; ++i) {
        v[i] = p[(q * 16 + i) * 1024];
        m = fmaxf(m, v[i]);
    }
    m = fmaxf(m, __shfl_xor(m, 1));
    m = fmaxf(m, __shfl_xor(m, 2));
    float s = 0.f;
#pragma unroll
    for (int i = 0; i < 16; ++i) { v[i] = expf(v[i] - m); s += v[i]; }
    s += __shfl_xor(s, 1);
    s += __shfl_xor(s, 2);
    float inv = 1.0f / s;
#pragma unroll
    for (int i = 0; i < 16; ++i) tile[nl][q * 16 + i] = f2bf(v[i] * inv);
    __syncthreads();
    ushort_t* ob = a_c2nT + ((size_t)h * 1024 + n0) * 64;
    for (int i = t; i < 512; i += 256) {
        int r = i >> 3, cq = i & 7;
        *(bf16x8*)&ob[r * 64 + cq * 8] = *(bf16x8*)&tile[r][cq * 8];
    }
}

// ---------- Wv transpose -> bf16 WvT[128][128] ----------
__global__ __launch_bounds__(256) void k_wprep_v(const float* __restrict__ Wv,
                                                 ushort_t* __restrict__ WvT) {
    __shared__ float tile[64][65];
    int b = blockIdx.x;
    int r0 = (b >> 1) * 64, c0 = (b & 1) * 64;
    int t = threadIdx.x;
    for (int i = t; i < 4096; i += 256) {
        int r = i >> 6, c = i & 63;
        tile[r][c] = Wv[(size_t)(r0 + r) * 128 + c0 + c];
    }
    __syncthreads();
    for (int i = t; i < 4096; i += 256) {
        int c = i >> 6, r = i & 63;
        WvT[(size_t)(c0 + c) * 128 + r0 + r] = f2bf(tile[r][c]);
    }
}

// ---------- W1 fragment-pack: W1f[ch][w][kk][jn][lane]*8 ----------
__global__ __launch_bounds__(256) void k_wpack1(const float* __restrict__ W1,
                                                ushort_t* __restrict__ W1f) {
    int tid = blockIdx.x * 256 + threadIdx.x;   // < 32768
    int lane = tid & 63, jn = (tid >> 6) & 1, kk = (tid >> 7) & 7;
    int w = (tid >> 10) & 3, ch = tid >> 12;
    int lr = lane & 15, lg = lane >> 4;
    int n = ch * 128 + w * 32 + jn * 16 + lr;
    int kb = kk * 32 + lg * 8;
    ushort_t o[8];
#pragma unroll
    for (int e = 0; e < 8; ++e) o[e] = f2bf(W1[(size_t)(kb + e) * 1024 + n]);
    *(bf16x8*)&W1f[(size_t)tid * 8] = *(bf16x8*)o;
}

// ---------- W2 fragment-pack: W2f[ch][w][kk][jy][lane]*8 ----------
__global__ __launch_bounds__(256) void k_wpack2(const float* __restrict__ W2,
                                                ushort_t* __restrict__ W2f) {
    int tid = blockIdx.x * 256 + threadIdx.x;   // < 16384
    int lane = tid & 63, jy = (tid >> 6) & 1, kk = (tid >> 7) & 3;
    int w = (tid >> 9) & 3, ch = tid >> 11;
    int lr = lane & 15, lg = lane >> 4;
    int f = w * 32 + jy * 16 + lr;
    int kb = ch * 128 + kk * 32 + lg * 8;
    ushort_t o[8];
#pragma unroll
    for (int e = 0; e < 8; ++e) o[e] = f2bf(W2[(size_t)(kb + e) * 128 + f]);
    *(bf16x8*)&W2f[(size_t)tid * 8] = *(bf16x8*)o;
}

// ---------- fused v-proj + stage1, 4-way n-split ----------
__global__ __launch_bounds__(256) void k_vs1(const float* __restrict__ input,
                                             const ushort_t* __restrict__ WvT,
                                             const float* __restrict__ bv,
                                             const ushort_t* __restrict__ a_n2c,
                                             float* __restrict__ T1p) {
    __shared__ __align__(16) ushort_t as_lds[128 * 128];
    __shared__ __align__(16) ushort_t vsT[128 * 128];
    int bt = blockIdx.x;
    int part = blockIdx.y;
    int t = threadIdx.x, w = t >> 6, lane = t & 63, lr = lane & 15, lg = lane >> 4;

    f32x4 t1acc[2][4];
#pragma unroll
    for (int hl = 0; hl < 2; ++hl)
#pragma unroll
        for (int mi = 0; mi < 4; ++mi) t1acc[hl][mi] = (f32x4){0.f, 0.f, 0.f, 0.f};

    for (int c8 = part * 2; c8 < part * 2 + 2; ++c8) {
        int n0 = c8 * 128;
        __syncthreads();
        for (int j = 0; j < 16; ++j) {
            int i = j * 256 + t;
            int r = i >> 5, cq = i & 31;
            float4 f = *(const float4*)&input[((size_t)(bt * 1024 + n0 + r)) * 128 + cq * 4];
            uint2 o;
            o.x = pk2(f.x, f.y);
            o.y = pk2(f.z, f.w);
            *(uint2*)swz256(as_lds, r, cq * 8) = o;
        }
        __syncthreads();
        f32x4 vacc[2][8];
#pragma unroll
        for (int mi = 0; mi < 2; ++mi)
#pragma unroll
            for (int jn = 0; jn < 8; ++jn) {
                float bb = bv[jn * 16 + lr];
                vacc[mi][jn] = (f32x4){bb, bb, bb, bb};
            }
#pragma unroll
        for (int ks = 0; ks < 4; ++ks) {
            bf16x8 a[2];
#pragma unroll
            for (int mi = 0; mi < 2; ++mi)
                a[mi] = *(const bf16x8*)swz256(as_lds, w * 32 + mi * 16 + lr, ks * 64 + lg * 16);
#pragma unroll
            for (int jn = 0; jn < 8; ++jn) {
                bf16x8 bfr = *(const bf16x8*)&WvT[(size_t)(jn * 16 + lr) * 128 + ks * 32 + lg * 8];
#pragma unroll
                for (int mi = 0; mi < 2; ++mi)
                    vacc[mi][jn] = __builtin_amdgcn_mfma_f32_16x16x32_bf16(a[mi], bfr, vacc[mi][jn], 0, 0, 0);
            }
        }
#pragma unroll
        for (int mi = 0; mi < 2; ++mi)
#pragma unroll
            for (int jn = 0; jn < 8; ++jn) {
                uint2 o;
                o.x = pk2(vacc[mi][jn][0], vacc[mi][jn][1]);
                o.y = pk2(vacc[mi][jn][2], vacc[mi][jn][3]);
                *(uint2*)swz256(vsT, jn * 16 + lr, w * 64 + mi * 32 + lg * 8) = o;
            }
        __syncthreads();
#pragma unroll
        for (int hl = 0; hl < 2; ++hl) {
            int h = w * 2 + hl;
#pragma unroll
            for (int ks = 0; ks < 4; ++ks) {
                bf16x8 bfr = *(const bf16x8*)swz256(vsT, h * 16 + lr, ks * 64 + lg * 16);
#pragma unroll
                for (int mi = 0; mi < 4; ++mi) {
                    bf16x8 a = *(const bf16x8*)&a_n2c[((size_t)(h * 64 + mi * 16 + lr)) * 1024 + n0 + ks * 32 + lg * 8];
                    t1acc[hl][mi] = __builtin_amdgcn_mfma_f32_16x16x32_bf16(a, bfr, t1acc[hl][mi], 0, 0, 0);
                }
            }
        }
    }
    float* op = T1p + (size_t)part * T1SZ;
#pragma unroll
    for (int hl = 0; hl < 2; ++hl) {
        int h = w * 2 + hl;
#pragma unroll
        for (int mi = 0; mi < 4; ++mi)
            *(f32x4*)&op[(((size_t)bt * 8 + h) * 16 + lr) * 64 + mi * 16 + lg * 4] = t1acc[hl][mi];
    }
}

// ---------- T1 partial reduce + bf16 convert ----------
__global__ __launch_bounds__(256) void k_t1conv(const float* __restrict__ T1p,
                                                ushort_t* __restrict__ T1t) {
    size_t i4 = ((size_t)blockIdx.x * 256 + threadIdx.x) * 4;
    float4 s = *(const float4*)&T1p[i4];
#pragma unroll
    for (int p = 1; p < 4; ++p) {
        float4 v = *(const float4*)&T1p[(size_t)p * T1SZ + i4];
        s.x += v.x; s.y += v.y; s.z += v.z; s.w += v.w;
    }
    uint2 o;
    o.x = pk2(s.x, s.y);
    o.y = pk2(s.z, s.w);
    *(uint2*)&T1t[i4] = o;
}

// ---------- fused MFMA FFN (R13 best-measured: 64-token, mailbox, cvt, setprio) ----------
__global__ __launch_bounds__(256) void k_ffn(
        const float* __restrict__ input,
        const ushort_t* __restrict__ a_c2nT,
        const ushort_t* __restrict__ T1t,
        const ushort_t* __restrict__ W1f,
        const ushort_t* __restrict__ W2f,
        const float* __restrict__ b1,
        const float* __restrict__ b2,
        float* __restrict__ out,
        float* __restrict__ bn_sum,
        float* __restrict__ bn_sq) {
    __shared__ __align__(16) ushort_t x2mb[4 * 8 * 64 * 8];   // 32 KB
    __shared__ __align__(16) ushort_t hmb[4 * 4 * 64 * 8];    // 16 KB
    int bt = blockIdx.y;
    int n0 = blockIdx.x * 64;
    int t = threadIdx.x;
    int w = t >> 6, lane = t & 63, lr = lane & 15, lg = lane >> 4;
    int R0 = w * 16;
    int rowbase = bt * 1024 + n0;

    // ---- phase A merged: vmix MFMA + input load + write both x2 halves ----
    {
        const ushort_t* tp = T1t + ((size_t)(bt * 128) + lr) * 64 + lg * 8;
        const ushort_t* ap = a_c2nT + ((size_t)(n0 + R0 + lr)) * 64 + lg * 8;
        ushort_t* mb = x2mb + w * 4096;
        int wbase = ((lg >> 1) * 16 + lr) * 8 + (lg & 1) * 4;
#pragma unroll
        for (int h = 0; h < 8; ++h) {
            f32x4 vacc = {0.f, 0.f, 0.f, 0.f};
#pragma unroll
            for (int kk = 0; kk < 2; ++kk) {
                bf16x8 af = *(const bf16x8*)(tp + h * 1024 + kk * 32);
                bf16x8 bf = *(const bf16x8*)(ap + (size_t)h * 65536 + kk * 32);
                vacc = __builtin_amdgcn_mfma_f32_16x16x32_bf16(af, bf, vacc, 0, 0, 0);
            }
            float4 inp = *(const float4*)&input[(size_t)(rowbase + R0 + lr) * 128 + h * 16 + lg * 4];
            uint2 lft, rgt;
            lft.x = pk2(inp.x - vacc[0], inp.y - vacc[1]);
            lft.y = pk2(inp.z - vacc[2], inp.w - vacc[3]);
            rgt.x = pk2(vacc[0], vacc[1]);
            rgt.y = pk2(vacc[2], vacc[3]);
            *(uint2*)&mb[wbase + h * 256]         = lft;
            *(uint2*)&mb[wbase + (h + 8) * 256]   = rgt;
        }
    }
    __syncthreads();

    // ---- y accumulators ----
    f32x4 yacc[4][2];
#pragma unroll
    for (int mi = 0; mi < 4; ++mi)
#pragma unroll
        for (int jy = 0; jy < 2; ++jy) {
            float bb = b2[w * 32 + jy * 16 + lr];
            yacc[mi][jy] = (f32x4){bb, bb, bb, bb};
        }

    int hwbase = w * 2048 + ((lg >> 1) * 16 + lr) * 8 + (lg & 1) * 4;

    for (int ch = 0; ch < 8; ++ch) {
        // prefetch GEMM2 B-fragments (packed, coalesced)
        bf16x8 b2r[4][2];
        {
            const ushort_t* w2p = W2f + (((size_t)(ch * 4 + w) * 4) * 2) * 512 + lane * 8;
#pragma unroll
            for (int kk = 0; kk < 4; ++kk)
#pragma unroll
                for (int jy = 0; jy < 2; ++jy)
                    b2r[kk][jy] = *(const bf16x8*)(w2p + (kk * 2 + jy) * 512);
        }

        // GEMM1 swapped
        f32x4 hacc[2][4];
#pragma unroll
        for (int jn = 0; jn < 2; ++jn) {
            f32x4 bb = *(const f32x4*)&b1[ch * 128 + w * 32 + jn * 16 + lg * 4];
#pragma unroll
            for (int mi = 0; mi < 4; ++mi) hacc[jn][mi] = bb;
        }
        const ushort_t* w1p = W1f + ((size_t)(ch * 4 + w) * 16) * 512 + lane * 8;
        __builtin_amdgcn_s_setprio(1);
#pragma unroll
        for (int kk = 0; kk < 8; ++kk) {
            bf16x8 xf[4];
#pragma unroll
            for (int mi = 0; mi < 4; ++mi)
                xf[mi] = *(const bf16x8*)&x2mb[mi * 4096 + kk * 512 + lane * 8];
#pragma unroll
            for (int jn = 0; jn < 2; ++jn) {
                bf16x8 wf = *(const bf16x8*)(w1p + (kk * 2 + jn) * 512);
#pragma unroll
                for (int mi = 0; mi < 4; ++mi)
                    hacc[jn][mi] = __builtin_amdgcn_mfma_f32_16x16x32_bf16(wf, xf[mi], hacc[jn][mi], 0, 0, 0);
            }
        }
        __builtin_amdgcn_s_setprio(0);
        __syncthreads();   // prev chunk's GEMM2 hmb reads complete
        // GELU -> hmb mailbox
#pragma unroll
        for (int jn = 0; jn < 2; ++jn)
#pragma unroll
            for (int mi = 0; mi < 4; ++mi) {
                uint2 o;
                o.x = pk2(gelu_f(hacc[jn][mi][0]), gelu_f(hacc[jn][mi][1]));
                o.y = pk2(gelu_f(hacc[jn][mi][2]), gelu_f(hacc[jn][mi][3]));
                *(uint2*)&hmb[hwbase + jn * 256 + mi * 512] = o;
            }
        __syncthreads();   // hmb visible
        // GEMM2 standard
        __builtin_amdgcn_s_setprio(1);
#pragma unroll
        for (int kk = 0; kk < 4; ++kk) {
            bf16x8 a4[4];
#pragma unroll
            for (int mi = 0; mi < 4; ++mi)
                a4[mi] = *(const bf16x8*)&hmb[kk * 2048 + mi * 512 + lane * 8];
#pragma unroll
            for (int jy = 0; jy < 2; ++jy)
#pragma unroll
                for (int mi = 0; mi < 4; ++mi)
                    yacc[mi][jy] = __builtin_amdgcn_mfma_f32_16x16x32_bf16(a4[mi], b2r[kk][jy], yacc[mi][jy], 0, 0, 0);
        }
        __builtin_amdgcn_s_setprio(0);
    }

    // ---- epilogue: residual + store + BN partials ----
    float sacc[2] = {0.f, 0.f}, qacc[2] = {0.f, 0.f};
#pragma unroll
    for (int mi = 0; mi < 4; ++mi)
#pragma unroll
        for (int jy = 0; jy < 2; ++jy)
#pragma unroll
            for (int r = 0; r < 4; ++r) {
                int gr = rowbase + mi * 16 + lg * 4 + r;
                int gc = w * 32 + jy * 16 + lr;
                float val = yacc[mi][jy][r] + input[(size_t)gr * 128 + gc];
                out[(size_t)gr * 128 + gc] = val;
                sacc[jy] += val;
                qacc[jy] += val * val;
            }
#pragma unroll
    for (int jy = 0; jy < 2; ++jy) {
        float s = sacc[jy], q = qacc[jy];
        s += __shfl_xor(s, 16); s += __shfl_xor(s, 32);
        q += __shfl_xor(q, 16); q += __shfl_xor(q, 32);
        if (lg == 0) {
            atomicAdd(&bn_sum[w * 32 + jy * 16 + lr], s);
            atomicAdd(&bn_sq[w * 32 + jy * 16 + lr], q);
        }
    }
}

// ---------- BN finalize ----------
__global__ void k_bnfin(const float* __restrict__ bn_sum, const float* __restrict__ bn_sq,
                        const float* __restrict__ gamma, const float* __restrict__ beta,
                        float* __restrict__ scale, float* __restrict__ shift) {
    int f = threadIdx.x;
    float mean = bn_sum[f] * (1.0f / CNT);
    float var  = bn_sq[f]  * (1.0f / CNT) - mean * mean;
    float sc = gamma[f] * rsqrtf(var + 1e-5f);
    scale[f] = sc;
    shift[f] = beta[f] - mean * sc;
}

// ---------- BN apply (in place) ----------
__global__ __launch_bounds__(256) void k_bnapply(float* __restrict__ out,
                                                 const float* __restrict__ scale,
                                                 const float* __restrict__ shift) {
    size_t idx = (size_t)blockIdx.x * 256 + threadIdx.x;
    int c = (int)((idx * 4) & 127);
    float4 v = *(float4*)&out[idx * 4];
    float4 sc = *(const float4*)&scale[c];
    float4 sh = *(const float4*)&shift[c];
    v.x = fmaf(v.x, sc.x, sh.x);
    v.y = fmaf(v.y, sc.y, sh.y);
    v.z = fmaf(v.z, sc.z, sh.z);
    v.w = fmaf(v.w, sc.w, sh.w);
    *(float4*)&out[idx * 4] = v;
}

extern "C" void kernel_launch(void* const* d_in, const int* in_sizes, int n_in,
                              void* d_out, int out_size, void* d_ws, size_t ws_size,
                              hipStream_t stream) {
    const float* input    = (const float*)d_in[0];
    const float* Wv       = (const float*)d_in[1];
    const float* bv       = (const float*)d_in[2];
    const float* adaptive = (const float*)d_in[3];
    const float* cores    = (const float*)d_in[4];
    const float* W1       = (const float*)d_in[5];
    const float* b1       = (const float*)d_in[6];
    const float* W2       = (const float*)d_in[7];
    const float* b2       = (const float*)d_in[8];
    const float* gamma    = (const float*)d_in[9];
    const float* beta     = (const float*)d_in[10];
    float* out = (float*)d_out;
    float* ws  = (float*)d_ws;

    float*    aff    = ws;                           // 524288 f
    ushort_t* a_n2c  = (ushort_t*)(ws + 524288);     // 524288 us
    ushort_t* a_c2nT = (ushort_t*)(ws + 786432);     // 524288 us
    ushort_t* T1t    = (ushort_t*)(ws + 1048576);    // 1572864 us
    ushort_t* W1f    = (ushort_t*)(ws + 1835008);    // 262144 us
    ushort_t* W2f    = (ushort_t*)(ws + 1966080);    // 131072 us
    ushort_t* WvT    = (ushort_t*)(ws + 2031616);    // 16384 us
    float* bn_sum    = ws + 2039808;
    float* bn_sq     = bn_sum + 128;
    float* scale     = bn_sum + 256;
    float* shift     = bn_sum + 384;
    float* T1p       = ws + 2097152;                 // 4 x T1SZ f

    k_sm_n   <<<512, 256, 0, stream>>>(cores, adaptive, aff, a_n2c);
    k_sm_c   <<<128, 256, 0, stream>>>(aff, a_c2nT);
    k_wprep_v<<<4, 256, 0, stream>>>(Wv, WvT);
    k_wpack1 <<<128, 256, 0, stream>>>(W1, W1f);
    k_wpack2 <<<64, 256, 0, stream>>>(W2, W2f);
    k_vs1    <<<dim3(BT, 4), 256, 0, stream>>>(input, WvT, bv, a_n2c, T1p);
    k_t1conv <<<1536, 256, 0, stream>>>(T1p, T1t);
    hipMemsetAsync(bn_sum, 0, 256 * sizeof(float), stream);
    k_ffn    <<<dim3(16, BT), 256, 0, stream>>>(input, a_c2nT, T1t, W1f, W2f,
                                                b1, b2, out, bn_sum, bn_sq);
    k_bnfin  <<<1, 128, 0, stream>>>(bn_sum, bn_sq, gamma, beta, scale, shift);
    k_bnapply<<<(out_size / 4) / 256, 256, 0, stream>>>(out, scale, shift);
}

// Round 17
// 397.231 us; speedup vs baseline: 1.0563x; 1.0127x over previous
//
#include <hip/hip_runtime.h>
#include <math.h>

// Problem constants
#define BB 16
#define TT 12
#define NN 1024
#define FF 128
#define BT 192
#define BTN 196608
#define CNT ((float)BTN)
#define T1SZ 1572864   // BT*8*16*64 elements

typedef unsigned short ushort_t;
typedef __attribute__((ext_vector_type(8))) short bf16x8;
typedef __attribute__((ext_vector_type(4))) float f32x4;

__device__ __forceinline__ ushort_t f2bf(float x) {
    union { float f; unsigned u; } c; c.f = x;
    unsigned r = c.u + 0x7fffu + ((c.u >> 16) & 1u);
    return (ushort_t)(r >> 16);
}
__device__ __forceinline__ float bf2f(ushort_t u) {
    union { unsigned u32; float f; } c; c.u32 = ((unsigned)u) << 16; return c.f;
}
// packed f32x2 -> bf16x2 via native v_cvt_pk_bf16_f32 (RNE), 1 VALU op.
__device__ __forceinline__ unsigned pk2(float a, float b) {
    unsigned r;
    asm("v_cvt_pk_bf16_f32 %0, %1, %2" : "=v"(r) : "v"(a), "v"(b));
    return r;
}
// tanh-form GELU
__device__ __forceinline__ float gelu_f(float x) {
    float u = x * x;
    float s = x * fmaf(u, -0.10294428f, -2.30220852f);
    float e = __builtin_amdgcn_exp2f(s);
    return x * __builtin_amdgcn_rcpf(1.0f + e);
}

// XOR-swizzle helper (k_vs1 only)
__device__ __forceinline__ char* swz256(void* base, int row, int byteoff) {
    return (char*)base + row * 256 + (byteoff ^ ((row & 7) << 4));
}

// ---------- fused aff + softmax over n -> bf16 a_n2c[h,c,n]; also writes aff ----------
__global__ __launch_bounds__(256) void k_sm_n(const float* __restrict__ cores,
                                              const float* __restrict__ adaptive,
                                              float* __restrict__ aff,
                                              ushort_t* __restrict__ out) {
    int row = blockIdx.x;                 // h*64+c
    int h = row >> 6;
    int t = threadIdx.x;
    __shared__ float red[8];
    const float* cp = cores + row * 16;
    const float* ap = adaptive + h * 16384;
    float v0 = 0.f, v1 = 0.f, v2 = 0.f, v3 = 0.f;
#pragma unroll
    for (int d = 0; d < 16; ++d) {
        float c = cp[d];
        const float* an = ap + d * 1024;
        v0 = fmaf(c, an[t], v0);
        v1 = fmaf(c, an[t + 256], v1);
        v2 = fmaf(c, an[t + 512], v2);
        v3 = fmaf(c, an[t + 768], v3);
    }
    v0 *= 0.25f; v1 *= 0.25f; v2 *= 0.25f; v3 *= 0.25f;
    aff[row * 1024 + t]       = v0;
    aff[row * 1024 + t + 256] = v1;
    aff[row * 1024 + t + 512] = v2;
    aff[row * 1024 + t + 768] = v3;
    float m = fmaxf(fmaxf(v0, v1), fmaxf(v2, v3));
#pragma unroll
    for (int off = 32; off >= 1; off >>= 1) m = fmaxf(m, __shfl_xor(m, off));
    if ((t & 63) == 0) red[t >> 6] = m;
    __syncthreads();
    m = fmaxf(fmaxf(red[0], red[1]), fmaxf(red[2], red[3]));
    v0 = expf(v0 - m); v1 = expf(v1 - m); v2 = expf(v2 - m); v3 = expf(v3 - m);
    float s = v0 + v1 + v2 + v3;
#pragma unroll
    for (int off = 32; off >= 1; off >>= 1) s += __shfl_xor(s, off);
    __syncthreads();
    if ((t & 63) == 0) red[4 + (t >> 6)] = s;
    __syncthreads();
    s = red[4] + red[5] + red[6] + red[7];
    float inv = 1.0f / s;
    out[row * 1024 + t]       = f2bf(v0 * inv);
    out[row * 1024 + t + 256] = f2bf(v1 * inv);
    out[row * 1024 + t + 512] = f2bf(v2 * inv);
    out[row * 1024 + t + 768] = f2bf(v3 * inv);
}

// ---------- softmax over c -> transposed bf16 a_c2nT[h][n][c] ----------
__global__ __launch_bounds__(256) void k_sm_c(const float* __restrict__ aff,
                                              ushort_t* __restrict__ a_c2nT) {
    __shared__ ushort_t tile[64][72];
    int b = blockIdx.x;
    int h = b >> 4, n0 = (b & 15) * 64;
    int t = threadIdx.x;
    int nl = t >> 2, q = t & 3;
    const float* p = aff + h * 65536 + n0 + nl;
    float v[16];
    float m = -1e30f;
#pragma unroll
    for (int i = 0; i < 16; ++i) {
        v[i] = p[(q * 16 + i) * 1024];
        m = fmaxf(m, v[i]);
    }
    m = fmaxf(m, __shfl_xor(m, 1));
    m = fmaxf(m, __shfl_xor(m, 2));
    float s = 0.f;
#pragma unroll
    for (int i = 0; i < 16; ++i) { v[i] = expf(v[i] - m); s += v[i]; }
    s += __shfl_xor(s, 1);
    s += __shfl_xor(s, 2);
    float inv = 1.0f / s;
#pragma unroll
    for (int i = 0; i < 16; ++i) tile[nl][q * 16 + i] = f2bf(v[i] * inv);
    __syncthreads();
    ushort_t* ob = a_c2nT + ((size_t)h * 1024 + n0) * 64;
    for (int i = t; i < 512; i += 256) {
        int r = i >> 3, cq = i & 7;
        *(bf16x8*)&ob[r * 64 + cq * 8] = *(bf16x8*)&tile[r][cq * 8];
    }
}

// ---------- Wv transpose -> bf16 WvT[128][128] ----------
__global__ __launch_bounds__(256) void k_wprep_v(const float* __restrict__ Wv,
                                                 ushort_t* __restrict__ WvT) {
    __shared__ float tile[64][65];
    int b = blockIdx.x;
    int r0 = (b >> 1) * 64, c0 = (b & 1) * 64;
    int t = threadIdx.x;
    for (int i = t; i < 4096; i += 256) {
        int r = i >> 6, c = i & 63;
        tile[r][c] = Wv[(size_t)(r0 + r) * 128 + c0 + c];
    }
    __syncthreads();
    for (int i = t; i < 4096; i += 256) {
        int c = i >> 6, r = i & 63;
        WvT[(size_t)(c0 + c) * 128 + r0 + r] = f2bf(tile[r][c]);
    }
}

// ---------- W1 fragment-pack: W1f[ch][w][kk][jn][lane]*8 ----------
__global__ __launch_bounds__(256) void k_wpack1(const float* __restrict__ W1,
                                                ushort_t* __restrict__ W1f) {
    int tid = blockIdx.x * 256 + threadIdx.x;   // < 32768
    int lane = tid & 63, jn = (tid >> 6) & 1, kk = (tid >> 7) & 7;
    int w = (tid >> 10) & 3, ch = tid >> 12;
    int lr = lane & 15, lg = lane >> 4;
    int n = ch * 128 + w * 32 + jn * 16 + lr;
    int kb = kk * 32 + lg * 8;
    ushort_t o[8];
#pragma unroll
    for (int e = 0; e < 8; ++e) o[e] = f2bf(W1[(size_t)(kb + e) * 1024 + n]);
    *(bf16x8*)&W1f[(size_t)tid * 8] = *(bf16x8*)o;
}

// ---------- W2 fragment-pack: W2f[ch][w][kk][jy][lane]*8 ----------
__global__ __launch_bounds__(256) void k_wpack2(const float* __restrict__ W2,
                                                ushort_t* __restrict__ W2f) {
    int tid = blockIdx.x * 256 + threadIdx.x;   // < 16384
    int lane = tid & 63, jy = (tid >> 6) & 1, kk = (tid >> 7) & 3;
    int w = (tid >> 9) & 3, ch = tid >> 11;
    int lr = lane & 15, lg = lane >> 4;
    int f = w * 32 + jy * 16 + lr;
    int kb = ch * 128 + kk * 32 + lg * 8;
    ushort_t o[8];
#pragma unroll
    for (int e = 0; e < 8; ++e) o[e] = f2bf(W2[(size_t)(kb + e) * 128 + f]);
    *(bf16x8*)&W2f[(size_t)tid * 8] = *(bf16x8*)o;
}

// ---------- fused v-proj + stage1, 4-way n-split ----------
__global__ __launch_bounds__(256) void k_vs1(const float* __restrict__ input,
                                             const ushort_t* __restrict__ WvT,
                                             const float* __restrict__ bv,
                                             const ushort_t* __restrict__ a_n2c,
                                             float* __restrict__ T1p) {
    __shared__ __align__(16) ushort_t as_lds[128 * 128];
    __shared__ __align__(16) ushort_t vsT[128 * 128];
    int bt = blockIdx.x;
    int part = blockIdx.y;
    int t = threadIdx.x, w = t >> 6, lane = t & 63, lr = lane & 15, lg = lane >> 4;

    f32x4 t1acc[2][4];
#pragma unroll
    for (int hl = 0; hl < 2; ++hl)
#pragma unroll
        for (int mi = 0; mi < 4; ++mi) t1acc[hl][mi] = (f32x4){0.f, 0.f, 0.f, 0.f};

    for (int c8 = part * 2; c8 < part * 2 + 2; ++c8) {
        int n0 = c8 * 128;
        __syncthreads();
        for (int j = 0; j < 16; ++j) {
            int i = j * 256 + t;
            int r = i >> 5, cq = i & 31;
            float4 f = *(const float4*)&input[((size_t)(bt * 1024 + n0 + r)) * 128 + cq * 4];
            uint2 o;
            o.x = pk2(f.x, f.y);
            o.y = pk2(f.z, f.w);
            *(uint2*)swz256(as_lds, r, cq * 8) = o;
        }
        __syncthreads();
        f32x4 vacc[2][8];
#pragma unroll
        for (int mi = 0; mi < 2; ++mi)
#pragma unroll
            for (int jn = 0; jn < 8; ++jn) {
                float bb = bv[jn * 16 + lr];
                vacc[mi][jn] = (f32x4){bb, bb, bb, bb};
            }
#pragma unroll
        for (int ks = 0; ks < 4; ++ks) {
            bf16x8 a[2];
#pragma unroll
            for (int mi = 0; mi < 2; ++mi)
                a[mi] = *(const bf16x8*)swz256(as_lds, w * 32 + mi * 16 + lr, ks * 64 + lg * 16);
#pragma unroll
            for (int jn = 0; jn < 8; ++jn) {
                bf16x8 bfr = *(const bf16x8*)&WvT[(size_t)(jn * 16 + lr) * 128 + ks * 32 + lg * 8];
#pragma unroll
                for (int mi = 0; mi < 2; ++mi)
                    vacc[mi][jn] = __builtin_amdgcn_mfma_f32_16x16x32_bf16(a[mi], bfr, vacc[mi][jn], 0, 0, 0);
            }
        }
#pragma unroll
        for (int mi = 0; mi < 2; ++mi)
#pragma unroll
            for (int jn = 0; jn < 8; ++jn) {
                uint2 o;
                o.x = pk2(vacc[mi][jn][0], vacc[mi][jn][1]);
                o.y = pk2(vacc[mi][jn][2], vacc[mi][jn][3]);
                *(uint2*)swz256(vsT, jn * 16 + lr, w * 64 + mi * 32 + lg * 8) = o;
            }
        __syncthreads();
#pragma unroll
        for (int hl = 0; hl < 2; ++hl) {
            int h = w * 2 + hl;
#pragma unroll
            for (int ks = 0; ks < 4; ++ks) {
                bf16x8 bfr = *(const bf16x8*)swz256(vsT, h * 16 + lr, ks * 64 + lg * 16);
#pragma unroll
                for (int mi = 0; mi < 4; ++mi) {
                    bf16x8 a = *(const bf16x8*)&a_n2c[((size_t)(h * 64 + mi * 16 + lr)) * 1024 + n0 + ks * 32 + lg * 8];
                    t1acc[hl][mi] = __builtin_amdgcn_mfma_f32_16x16x32_bf16(a, bfr, t1acc[hl][mi], 0, 0, 0);
                }
            }
        }
    }
    float* op = T1p + (size_t)part * T1SZ;
#pragma unroll
    for (int hl = 0; hl < 2; ++hl) {
        int h = w * 2 + hl;
#pragma unroll
        for (int mi = 0; mi < 4; ++mi)
            *(f32x4*)&op[(((size_t)bt * 8 + h) * 16 + lr) * 64 + mi * 16 + lg * 4] = t1acc[hl][mi];
    }
}

// ---------- T1 partial reduce + bf16 convert ----------
__global__ __launch_bounds__(256) void k_t1conv(const float* __restrict__ T1p,
                                                ushort_t* __restrict__ T1t) {
    size_t i4 = ((size_t)blockIdx.x * 256 + threadIdx.x) * 4;
    float4 s = *(const float4*)&T1p[i4];
#pragma unroll
    for (int p = 1; p < 4; ++p) {
        float4 v = *(const float4*)&T1p[(size_t)p * T1SZ + i4];
        s.x += v.x; s.y += v.y; s.z += v.z; s.w += v.w;
    }
    uint2 o;
    o.x = pk2(s.x, s.y);
    o.y = pk2(s.z, s.w);
    *(uint2*)&T1t[i4] = o;
}

// ---------- fused MFMA FFN: R13 base + cross-chunk software pipeline ----------
// Per chunk pair: [bar; GELU(A); bar; GEMM1(next)->B; GEMM2(cur)] — the region
// after the publish-bar holds 96 consolidated MFMA independent of fresh hmb.
__global__ __launch_bounds__(256) void k_ffn(
        const float* __restrict__ input,
        const ushort_t* __restrict__ a_c2nT,
        const ushort_t* __restrict__ T1t,
        const ushort_t* __restrict__ W1f,
        const ushort_t* __restrict__ W2f,
        const float* __restrict__ b1,
        const float* __restrict__ b2,
        float* __restrict__ out,
        float* __restrict__ bn_sum,
        float* __restrict__ bn_sq) {
    __shared__ __align__(16) ushort_t x2mb[4 * 8 * 64 * 8];   // 32 KB
    __shared__ __align__(16) ushort_t hmb[4 * 4 * 64 * 8];    // 16 KB
    int bt = blockIdx.y;
    int n0 = blockIdx.x * 64;
    int t = threadIdx.x;
    int w = t >> 6, lane = t & 63, lr = lane & 15, lg = lane >> 4;
    int R0 = w * 16;
    int rowbase = bt * 1024 + n0;

    // ---- phase A merged: vmix MFMA + input load + write both x2 halves ----
    {
        const ushort_t* tp = T1t + ((size_t)(bt * 128) + lr) * 64 + lg * 8;
        const ushort_t* ap = a_c2nT + ((size_t)(n0 + R0 + lr)) * 64 + lg * 8;
        ushort_t* mb = x2mb + w * 4096;
        int wbase = ((lg >> 1) * 16 + lr) * 8 + (lg & 1) * 4;
#pragma unroll
        for (int h = 0; h < 8; ++h) {
            f32x4 vacc = {0.f, 0.f, 0.f, 0.f};
#pragma unroll
            for (int kk = 0; kk < 2; ++kk) {
                bf16x8 af = *(const bf16x8*)(tp + h * 1024 + kk * 32);
                bf16x8 bf = *(const bf16x8*)(ap + (size_t)h * 65536 + kk * 32);
                vacc = __builtin_amdgcn_mfma_f32_16x16x32_bf16(af, bf, vacc, 0, 0, 0);
            }
            float4 inp = *(const float4*)&input[(size_t)(rowbase + R0 + lr) * 128 + h * 16 + lg * 4];
            uint2 lft, rgt;
            lft.x = pk2(inp.x - vacc[0], inp.y - vacc[1]);
            lft.y = pk2(inp.z - vacc[2], inp.w - vacc[3]);
            rgt.x = pk2(vacc[0], vacc[1]);
            rgt.y = pk2(vacc[2], vacc[3]);
            *(uint2*)&mb[wbase + h * 256]         = lft;
            *(uint2*)&mb[wbase + (h + 8) * 256]   = rgt;
        }
    }
    __syncthreads();

    // ---- y accumulators ----
    f32x4 yacc[4][2];
#pragma unroll
    for (int mi = 0; mi < 4; ++mi)
#pragma unroll
        for (int jy = 0; jy < 2; ++jy) {
            float bb = b2[w * 32 + jy * 16 + lr];
            yacc[mi][jy] = (f32x4){bb, bb, bb, bb};
        }

    int hwbase = w * 2048 + ((lg >> 1) * 16 + lr) * 8 + (lg & 1) * 4;

    // GEMM1 of chunk `ch` into the given accumulator (macro: static buffer names)
#define GEMM1_INTO(HACC, CH) {                                                        \
        _Pragma("unroll")                                                             \
        for (int jn = 0; jn < 2; ++jn) {                                              \
            f32x4 bb = *(const f32x4*)&b1[(CH) * 128 + w * 32 + jn * 16 + lg * 4];    \
            _Pragma("unroll")                                                         \
            for (int mi = 0; mi < 4; ++mi) HACC[jn][mi] = bb;                         \
        }                                                                             \
        const ushort_t* w1p = W1f + ((size_t)((CH) * 4 + w) * 16) * 512 + lane * 8;   \
        __builtin_amdgcn_s_setprio(1);                                                \
        _Pragma("unroll")                                                             \
        for (int kk = 0; kk < 8; ++kk) {                                              \
            bf16x8 xf[4];                                                             \
            _Pragma("unroll")                                                         \
            for (int mi = 0; mi < 4; ++mi)                                            \
                xf[mi] = *(const bf16x8*)&x2mb[mi * 4096 + kk * 512 + lane * 8];      \
            _Pragma("unroll")                                                         \
            for (int jn = 0; jn < 2; ++jn) {                                          \
                bf16x8 wf = *(const bf16x8*)(w1p + (kk * 2 + jn) * 512);              \
                _Pragma("unroll")                                                     \
                for (int mi = 0; mi < 4; ++mi)                                        \
                    HACC[jn][mi] = __builtin_amdgcn_mfma_f32_16x16x32_bf16(wf, xf[mi], HACC[jn][mi], 0, 0, 0); \
            }                                                                         \
        }                                                                             \
        __builtin_amdgcn_s_setprio(0);                                                \
    }

#define GELU_STORE(HACC) {                                                            \
        _Pragma("unroll")                                                             \
        for (int jn = 0; jn < 2; ++jn)                                                \
            _Pragma("unroll")                                                         \
            for (int mi = 0; mi < 4; ++mi) {                                          \
                uint2 o;                                                              \
                o.x = pk2(gelu_f(HACC[jn][mi][0]), gelu_f(HACC[jn][mi][1]));          \
                o.y = pk2(gelu_f(HACC[jn][mi][2]), gelu_f(HACC[jn][mi][3]));          \
                *(uint2*)&hmb[hwbase + jn * 256 + mi * 512] = o;                      \
            }                                                                         \
    }

#define GEMM2_CHUNK(CH) {                                                             \
        bf16x8 b2r[4][2];                                                             \
        const ushort_t* w2p = W2f + (((size_t)((CH) * 4 + w) * 4) * 2) * 512 + lane * 8; \
        _Pragma("unroll")                                                             \
        for (int kk = 0; kk < 4; ++kk)                                                \
            _Pragma("unroll")                                                         \
            for (int jy = 0; jy < 2; ++jy)                                            \
                b2r[kk][jy] = *(const bf16x8*)(w2p + (kk * 2 + jy) * 512);            \
        __builtin_amdgcn_s_setprio(1);                                                \
        _Pragma("unroll")                                                             \
        for (int kk = 0; kk < 4; ++kk) {                                              \
            bf16x8 a4[4];                                                             \
            _Pragma("unroll")                                                         \
            for (int mi = 0; mi < 4; ++mi)                                            \
                a4[mi] = *(const bf16x8*)&hmb[kk * 2048 + mi * 512 + lane * 8];       \
            _Pragma("unroll")                                                         \
            for (int jy = 0; jy < 2; ++jy)                                            \
                _Pragma("unroll")                                                     \
                for (int mi = 0; mi < 4; ++mi)                                        \
                    yacc[mi][jy] = __builtin_amdgcn_mfma_f32_16x16x32_bf16(a4[mi], b2r[kk][jy], yacc[mi][jy], 0, 0, 0); \
        }                                                                             \
        __builtin_amdgcn_s_setprio(0);                                                \
    }

    f32x4 haccA[2][4], haccB[2][4];
    GEMM1_INTO(haccA, 0);
#pragma unroll
    for (int cc = 0; cc < 4; ++cc) {
        int ch = cc * 2;
        __syncthreads();            // prev GEMM2 hmb reads complete
        GELU_STORE(haccA);
        __syncthreads();            // hmb(ch) published
        GEMM1_INTO(haccB, ch + 1);  // independent MFMA fills the region
        GEMM2_CHUNK(ch);
        __syncthreads();            // GEMM2(ch) hmb reads complete
        GELU_STORE(haccB);
        __syncthreads();            // hmb(ch+1) published
        if (cc < 3) GEMM1_INTO(haccA, ch + 2);
        GEMM2_CHUNK(ch + 1);
    }
#undef GEMM1_INTO
#undef GELU_STORE
#undef GEMM2_CHUNK

    // ---- epilogue: residual + store + BN partials ----
    float sacc[2] = {0.f, 0.f}, qacc[2] = {0.f, 0.f};
#pragma unroll
    for (int mi = 0; mi < 4; ++mi)
#pragma unroll
        for (int jy = 0; jy < 2; ++jy)
#pragma unroll
            for (int r = 0; r < 4; ++r) {
                int gr = rowbase + mi * 16 + lg * 4 + r;
                int gc = w * 32 + jy * 16 + lr;
                float val = yacc[mi][jy][r] + input[(size_t)gr * 128 + gc];
                out[(size_t)gr * 128 + gc] = val;
                sacc[jy] += val;
                qacc[jy] += val * val;
            }
#pragma unroll
    for (int jy = 0; jy < 2; ++jy) {
        float s = sacc[jy], q = qacc[jy];
        s += __shfl_xor(s, 16); s += __shfl_xor(s, 32);
        q += __shfl_xor(q, 16); q += __shfl_xor(q, 32);
        if (lg == 0) {
            atomicAdd(&bn_sum[w * 32 + jy * 16 + lr], s);
            atomicAdd(&bn_sq[w * 32 + jy * 16 + lr], q);
        }
    }
}

// ---------- BN finalize ----------
__global__ void k_bnfin(const float* __restrict__ bn_sum, const float* __restrict__ bn_sq,
                        const float* __restrict__ gamma, const float* __restrict__ beta,
                        float* __restrict__ scale, float* __restrict__ shift) {
    int f = threadIdx.x;
    float mean = bn_sum[f] * (1.0f / CNT);
    float var  = bn_sq[f]  * (1.0f / CNT) - mean * mean;
    float sc = gamma[f] * rsqrtf(var + 1e-5f);
    scale[f] = sc;
    shift[f] = beta[f] - mean * sc;
}

// ---------- BN apply (in place) ----------
__global__ __launch_bounds__(256) void k_bnapply(float* __restrict__ out,
                                                 const float* __restrict__ scale,
                                                 const float* __restrict__ shift) {
    size_t idx = (size_t)blockIdx.x * 256 + threadIdx.x;
    int c = (int)((idx * 4) & 127);
    float4 v = *(float4*)&out[idx * 4];
    float4 sc = *(const float4*)&scale[c];
    float4 sh = *(const float4*)&shift[c];
    v.x = fmaf(v.x, sc.x, sh.x);
    v.y = fmaf(v.y, sc.y, sh.y);
    v.z = fmaf(v.z, sc.z, sh.z);
    v.w = fmaf(v.w, sc.w, sh.w);
    *(float4*)&out[idx * 4] = v;
}

extern "C" void kernel_launch(void* const* d_in, const int* in_sizes, int n_in,
                              void* d_out, int out_size, void* d_ws, size_t ws_size,
                              hipStream_t stream) {
    const float* input    = (const float*)d_in[0];
    const float* Wv       = (const float*)d_in[1];
    const float* bv       = (const float*)d_in[2];
    const float* adaptive = (const float*)d_in[3];
    const float* cores    = (const float*)d_in[4];
    const float* W1       = (const float*)d_in[5];
    const float* b1       = (const float*)d_in[6];
    const float* W2       = (const float*)d_in[7];
    const float* b2       = (const float*)d_in[8];
    const float* gamma    = (const float*)d_in[9];
    const float* beta     = (const float*)d_in[10];
    float* out = (float*)d_out;
    float* ws  = (float*)d_ws;

    float*    aff    = ws;                           // 524288 f
    ushort_t* a_n2c  = (ushort_t*)(ws + 524288);     // 524288 us
    ushort_t* a_c2nT = (ushort_t*)(ws + 786432);     // 524288 us
    ushort_t* T1t    = (ushort_t*)(ws + 1048576);    // 1572864 us
    ushort_t* W1f    = (ushort_t*)(ws + 1835008);    // 262144 us
    ushort_t* W2f    = (ushort_t*)(ws + 1966080);    // 131072 us
    ushort_t* WvT    = (ushort_t*)(ws + 2031616);    // 16384 us
    float* bn_sum    = ws + 2039808;
    float* bn_sq     = bn_sum + 128;
    float* scale     = bn_sum + 256;
    float* shift     = bn_sum + 384;
    float* T1p       = ws + 2097152;                 // 4 x T1SZ f

    k_sm_n   <<<512, 256, 0, stream>>>(cores, adaptive, aff, a_n2c);
    k_sm_c   <<<128, 256, 0, stream>>>(aff, a_c2nT);
    k_wprep_v<<<4, 256, 0, stream>>>(Wv, WvT);
    k_wpack1 <<<128, 256, 0, stream>>>(W1, W1f);
    k_wpack2 <<<64, 256, 0, stream>>>(W2, W2f);
    k_vs1    <<<dim3(BT, 4), 256, 0, stream>>>(input, WvT, bv, a_n2c, T1p);
    k_t1conv <<<1536, 256, 0, stream>>>(T1p, T1t);
    hipMemsetAsync(bn_sum, 0, 256 * sizeof(float), stream);
    k_ffn    <<<dim3(16, BT), 256, 0, stream>>>(input, a_c2nT, T1t, W1f, W2f,
                                                b1, b2, out, bn_sum, bn_sq);
    k_bnfin  <<<1, 128, 0, stream>>>(bn_sum, bn_sq, gamma, beta, scale, shift);
    k_bnapply<<<(out_size / 4) / 256, 256, 0, stream>>>(out, scale, shift);
}

// Round 18
// 386.465 us; speedup vs baseline: 1.0857x; 1.0279x over previous
//
#include <hip/hip_runtime.h>
#include <math.h>

// Problem constants
#define BB 16
#define TT 12
#define NN 1024
#define FF 128
#define BT 192
#define BTN 196608
#define CNT ((float)BTN)
#define T1SZ 1572864   // BT*8*16*64 elements

typedef unsigned short ushort_t;
typedef __attribute__((ext_vector_type(8))) short bf16x8;
typedef __attribute__((ext_vector_type(4))) float f32x4;

__device__ __forceinline__ ushort_t f2bf(float x) {
    union { float f; unsigned u; } c; c.f = x;
    unsigned r = c.u + 0x7fffu + ((c.u >> 16) & 1u);
    return (ushort_t)(r >> 16);
}
__device__ __forceinline__ float bf2f(ushort_t u) {
    union { unsigned u32; float f; } c; c.u32 = ((unsigned)u) << 16; return c.f;
}
// packed f32x2 -> bf16x2 via native v_cvt_pk_bf16_f32 (RNE), 1 VALU op.
__device__ __forceinline__ unsigned pk2(float a, float b) {
    unsigned r;
    asm("v_cvt_pk_bf16_f32 %0, %1, %2" : "=v"(r) : "v"(a), "v"(b));
    return r;
}
// tanh-form GELU
__device__ __forceinline__ float gelu_f(float x) {
    float u = x * x;
    float s = x * fmaf(u, -0.10294428f, -2.30220852f);
    float e = __builtin_amdgcn_exp2f(s);
    return x * __builtin_amdgcn_rcpf(1.0f + e);
}

// XOR-swizzle helper (k_vs1 only)
__device__ __forceinline__ char* swz256(void* base, int row, int byteoff) {
    return (char*)base + row * 256 + (byteoff ^ ((row & 7) << 4));
}

// ---------- fused aff + softmax over n -> bf16 a_n2c[h,c,n]; also writes aff ----------
__global__ __launch_bounds__(256) void k_sm_n(const float* __restrict__ cores,
                                              const float* __restrict__ adaptive,
                                              float* __restrict__ aff,
                                              ushort_t* __restrict__ out) {
    int row = blockIdx.x;                 // h*64+c
    int h = row >> 6;
    int t = threadIdx.x;
    __shared__ float red[8];
    const float* cp = cores + row * 16;
    const float* ap = adaptive + h * 16384;
    float v0 = 0.f, v1 = 0.f, v2 = 0.f, v3 = 0.f;
#pragma unroll
    for (int d = 0; d < 16; ++d) {
        float c = cp[d];
        const float* an = ap + d * 1024;
        v0 = fmaf(c, an[t], v0);
        v1 = fmaf(c, an[t + 256], v1);
        v2 = fmaf(c, an[t + 512], v2);
        v3 = fmaf(c, an[t + 768], v3);
    }
    v0 *= 0.25f; v1 *= 0.25f; v2 *= 0.25f; v3 *= 0.25f;
    aff[row * 1024 + t]       = v0;
    aff[row * 1024 + t + 256] = v1;
    aff[row * 1024 + t + 512] = v2;
    aff[row * 1024 + t + 768] = v3;
    float m = fmaxf(fmaxf(v0, v1), fmaxf(v2, v3));
#pragma unroll
    for (int off = 32; off >= 1; off >>= 1) m = fmaxf(m, __shfl_xor(m, off));
    if ((t & 63) == 0) red[t >> 6] = m;
    __syncthreads();
    m = fmaxf(fmaxf(red[0], red[1]), fmaxf(red[2], red[3]));
    v0 = expf(v0 - m); v1 = expf(v1 - m); v2 = expf(v2 - m); v3 = expf(v3 - m);
    float s = v0 + v1 + v2 + v3;
#pragma unroll
    for (int off = 32; off >= 1; off >>= 1) s += __shfl_xor(s, off);
    __syncthreads();
    if ((t & 63) == 0) red[4 + (t >> 6)] = s;
    __syncthreads();
    s = red[4] + red[5] + red[6] + red[7];
    float inv = 1.0f / s;
    out[row * 1024 + t]       = f2bf(v0 * inv);
    out[row * 1024 + t + 256] = f2bf(v1 * inv);
    out[row * 1024 + t + 512] = f2bf(v2 * inv);
    out[row * 1024 + t + 768] = f2bf(v3 * inv);
}

// ---------- merged prep: sm_c (128) | WvT (4) | wpack1 (128) | wpack2 (64) | zero (1) ----------
__global__ __launch_bounds__(256) void k_prep(const float* __restrict__ aff,
                                              const float* __restrict__ Wv,
                                              const float* __restrict__ W1,
                                              const float* __restrict__ W2,
                                              ushort_t* __restrict__ a_c2nT,
                                              ushort_t* __restrict__ WvT,
                                              ushort_t* __restrict__ W1f,
                                              ushort_t* __restrict__ W2f,
                                              float* __restrict__ bn_sum) {
    __shared__ __align__(16) char smem[64 * 65 * 4];
    int b = blockIdx.x;
    int t = threadIdx.x;
    if (b < 128) {
        // ---- softmax over c -> transposed bf16 a_c2nT[h][n][c] ----
        ushort_t (*tile)[72] = (ushort_t(*)[72])smem;
        int h = b >> 4, n0 = (b & 15) * 64;
        int nl = t >> 2, q = t & 3;
        const float* p = aff + h * 65536 + n0 + nl;
        float v[16];
        float m = -1e30f;
#pragma unroll
        for (int i = 0; i < 16; ++i) {
            v[i] = p[(q * 16 + i) * 1024];
            m = fmaxf(m, v[i]);
        }
        m = fmaxf(m, __shfl_xor(m, 1));
        m = fmaxf(m, __shfl_xor(m, 2));
        float s = 0.f;
#pragma unroll
        for (int i = 0; i < 16; ++i) { v[i] = expf(v[i] - m); s += v[i]; }
        s += __shfl_xor(s, 1);
        s += __shfl_xor(s, 2);
        float inv = 1.0f / s;
#pragma unroll
        for (int i = 0; i < 16; ++i) tile[nl][q * 16 + i] = f2bf(v[i] * inv);
        __syncthreads();
        ushort_t* ob = a_c2nT + ((size_t)h * 1024 + n0) * 64;
        for (int i = t; i < 512; i += 256) {
            int r = i >> 3, cq = i & 7;
            *(bf16x8*)&ob[r * 64 + cq * 8] = *(bf16x8*)&tile[r][cq * 8];
        }
    } else if (b < 132) {
        // ---- Wv transpose -> bf16 WvT[128][128] ----
        float (*tile)[65] = (float(*)[65])smem;
        int q = b - 128;
        int r0 = (q >> 1) * 64, c0 = (q & 1) * 64;
        for (int i = t; i < 4096; i += 256) {
            int r = i >> 6, c = i & 63;
            tile[r][c] = Wv[(size_t)(r0 + r) * 128 + c0 + c];
        }
        __syncthreads();
        for (int i = t; i < 4096; i += 256) {
            int c = i >> 6, r = i & 63;
            WvT[(size_t)(c0 + c) * 128 + r0 + r] = f2bf(tile[r][c]);
        }
    } else if (b < 260) {
        // ---- W1 fragment-pack ----
        int tid = (b - 132) * 256 + t;   // < 32768
        int lane = tid & 63, jn = (tid >> 6) & 1, kk = (tid >> 7) & 7;
        int w = (tid >> 10) & 3, ch = tid >> 12;
        int lr = lane & 15, lg = lane >> 4;
        int n = ch * 128 + w * 32 + jn * 16 + lr;
        int kb = kk * 32 + lg * 8;
        ushort_t o[8];
#pragma unroll
        for (int e = 0; e < 8; ++e) o[e] = f2bf(W1[(size_t)(kb + e) * 1024 + n]);
        *(bf16x8*)&W1f[(size_t)tid * 8] = *(bf16x8*)o;
    } else if (b < 324) {
        // ---- W2 fragment-pack ----
        int tid = (b - 260) * 256 + t;   // < 16384
        int lane = tid & 63, jy = (tid >> 6) & 1, kk = (tid >> 7) & 3;
        int w = (tid >> 9) & 3, ch = tid >> 11;
        int lr = lane & 15, lg = lane >> 4;
        int f = w * 32 + jy * 16 + lr;
        int kb = ch * 128 + kk * 32 + lg * 8;
        ushort_t o[8];
#pragma unroll
        for (int e = 0; e < 8; ++e) o[e] = f2bf(W2[(size_t)(kb + e) * 128 + f]);
        *(bf16x8*)&W2f[(size_t)tid * 8] = *(bf16x8*)o;
    } else {
        // ---- zero bn_sum + bn_sq (256 floats) ----
        bn_sum[t] = 0.f;
    }
}

// ---------- fused v-proj + stage1, 4-way n-split ----------
__global__ __launch_bounds__(256) void k_vs1(const float* __restrict__ input,
                                             const ushort_t* __restrict__ WvT,
                                             const float* __restrict__ bv,
                                             const ushort_t* __restrict__ a_n2c,
                                             float* __restrict__ T1p) {
    __shared__ __align__(16) ushort_t as_lds[128 * 128];
    __shared__ __align__(16) ushort_t vsT[128 * 128];
    int bt = blockIdx.x;
    int part = blockIdx.y;
    int t = threadIdx.x, w = t >> 6, lane = t & 63, lr = lane & 15, lg = lane >> 4;

    f32x4 t1acc[2][4];
#pragma unroll
    for (int hl = 0; hl < 2; ++hl)
#pragma unroll
        for (int mi = 0; mi < 4; ++mi) t1acc[hl][mi] = (f32x4){0.f, 0.f, 0.f, 0.f};

    for (int c8 = part * 2; c8 < part * 2 + 2; ++c8) {
        int n0 = c8 * 128;
        __syncthreads();
        for (int j = 0; j < 16; ++j) {
            int i = j * 256 + t;
            int r = i >> 5, cq = i & 31;
            float4 f = *(const float4*)&input[((size_t)(bt * 1024 + n0 + r)) * 128 + cq * 4];
            uint2 o;
            o.x = pk2(f.x, f.y);
            o.y = pk2(f.z, f.w);
            *(uint2*)swz256(as_lds, r, cq * 8) = o;
        }
        __syncthreads();
        f32x4 vacc[2][8];
#pragma unroll
        for (int mi = 0; mi < 2; ++mi)
#pragma unroll
            for (int jn = 0; jn < 8; ++jn) {
                float bb = bv[jn * 16 + lr];
                vacc[mi][jn] = (f32x4){bb, bb, bb, bb};
            }
#pragma unroll
        for (int ks = 0; ks < 4; ++ks) {
            bf16x8 a[2];
#pragma unroll
            for (int mi = 0; mi < 2; ++mi)
                a[mi] = *(const bf16x8*)swz256(as_lds, w * 32 + mi * 16 + lr, ks * 64 + lg * 16);
#pragma unroll
            for (int jn = 0; jn < 8; ++jn) {
                bf16x8 bfr = *(const bf16x8*)&WvT[(size_t)(jn * 16 + lr) * 128 + ks * 32 + lg * 8];
#pragma unroll
                for (int mi = 0; mi < 2; ++mi)
                    vacc[mi][jn] = __builtin_amdgcn_mfma_f32_16x16x32_bf16(a[mi], bfr, vacc[mi][jn], 0, 0, 0);
            }
        }
#pragma unroll
        for (int mi = 0; mi < 2; ++mi)
#pragma unroll
            for (int jn = 0; jn < 8; ++jn) {
                uint2 o;
                o.x = pk2(vacc[mi][jn][0], vacc[mi][jn][1]);
                o.y = pk2(vacc[mi][jn][2], vacc[mi][jn][3]);
                *(uint2*)swz256(vsT, jn * 16 + lr, w * 64 + mi * 32 + lg * 8) = o;
            }
        __syncthreads();
#pragma unroll
        for (int hl = 0; hl < 2; ++hl) {
            int h = w * 2 + hl;
#pragma unroll
            for (int ks = 0; ks < 4; ++ks) {
                bf16x8 bfr = *(const bf16x8*)swz256(vsT, h * 16 + lr, ks * 64 + lg * 16);
#pragma unroll
                for (int mi = 0; mi < 4; ++mi) {
                    bf16x8 a = *(const bf16x8*)&a_n2c[((size_t)(h * 64 + mi * 16 + lr)) * 1024 + n0 + ks * 32 + lg * 8];
                    t1acc[hl][mi] = __builtin_amdgcn_mfma_f32_16x16x32_bf16(a, bfr, t1acc[hl][mi], 0, 0, 0);
                }
            }
        }
    }
    float* op = T1p + (size_t)part * T1SZ;
#pragma unroll
    for (int hl = 0; hl < 2; ++hl) {
        int h = w * 2 + hl;
#pragma unroll
        for (int mi = 0; mi < 4; ++mi)
            *(f32x4*)&op[(((size_t)bt * 8 + h) * 16 + lr) * 64 + mi * 16 + lg * 4] = t1acc[hl][mi];
    }
}

// ---------- T1 partial reduce + bf16 convert ----------
__global__ __launch_bounds__(256) void k_t1conv(const float* __restrict__ T1p,
                                                ushort_t* __restrict__ T1t) {
    size_t i4 = ((size_t)blockIdx.x * 256 + threadIdx.x) * 4;
    float4 s = *(const float4*)&T1p[i4];
#pragma unroll
    for (int p = 1; p < 4; ++p) {
        float4 v = *(const float4*)&T1p[(size_t)p * T1SZ + i4];
        s.x += v.x; s.y += v.y; s.z += v.z; s.w += v.w;
    }
    uint2 o;
    o.x = pk2(s.x, s.y);
    o.y = pk2(s.z, s.w);
    *(uint2*)&T1t[i4] = o;
}

// ---------- fused MFMA FFN (R17: mailbox + cvt + setprio + SW pipeline) ----------
__global__ __launch_bounds__(256) void k_ffn(
        const float* __restrict__ input,
        const ushort_t* __restrict__ a_c2nT,
        const ushort_t* __restrict__ T1t,
        const ushort_t* __restrict__ W1f,
        const ushort_t* __restrict__ W2f,
        const float* __restrict__ b1,
        const float* __restrict__ b2,
        float* __restrict__ out,
        float* __restrict__ bn_sum,
        float* __restrict__ bn_sq) {
    __shared__ __align__(16) ushort_t x2mb[4 * 8 * 64 * 8];   // 32 KB
    __shared__ __align__(16) ushort_t hmb[4 * 4 * 64 * 8];    // 16 KB
    int bt = blockIdx.y;
    int n0 = blockIdx.x * 64;
    int t = threadIdx.x;
    int w = t >> 6, lane = t & 63, lr = lane & 15, lg = lane >> 4;
    int R0 = w * 16;
    int rowbase = bt * 1024 + n0;

    // ---- phase A merged: vmix MFMA + input load + write both x2 halves ----
    {
        const ushort_t* tp = T1t + ((size_t)(bt * 128) + lr) * 64 + lg * 8;
        const ushort_t* ap = a_c2nT + ((size_t)(n0 + R0 + lr)) * 64 + lg * 8;
        ushort_t* mb = x2mb + w * 4096;
        int wbase = ((lg >> 1) * 16 + lr) * 8 + (lg & 1) * 4;
#pragma unroll
        for (int h = 0; h < 8; ++h) {
            f32x4 vacc = {0.f, 0.f, 0.f, 0.f};
#pragma unroll
            for (int kk = 0; kk < 2; ++kk) {
                bf16x8 af = *(const bf16x8*)(tp + h * 1024 + kk * 32);
                bf16x8 bf = *(const bf16x8*)(ap + (size_t)h * 65536 + kk * 32);
                vacc = __builtin_amdgcn_mfma_f32_16x16x32_bf16(af, bf, vacc, 0, 0, 0);
            }
            float4 inp = *(const float4*)&input[(size_t)(rowbase + R0 + lr) * 128 + h * 16 + lg * 4];
            uint2 lft, rgt;
            lft.x = pk2(inp.x - vacc[0], inp.y - vacc[1]);
            lft.y = pk2(inp.z - vacc[2], inp.w - vacc[3]);
            rgt.x = pk2(vacc[0], vacc[1]);
            rgt.y = pk2(vacc[2], vacc[3]);
            *(uint2*)&mb[wbase + h * 256]         = lft;
            *(uint2*)&mb[wbase + (h + 8) * 256]   = rgt;
        }
    }
    __syncthreads();

    // ---- y accumulators ----
    f32x4 yacc[4][2];
#pragma unroll
    for (int mi = 0; mi < 4; ++mi)
#pragma unroll
        for (int jy = 0; jy < 2; ++jy) {
            float bb = b2[w * 32 + jy * 16 + lr];
            yacc[mi][jy] = (f32x4){bb, bb, bb, bb};
        }

    int hwbase = w * 2048 + ((lg >> 1) * 16 + lr) * 8 + (lg & 1) * 4;

#define GEMM1_INTO(HACC, CH) {                                                        \
        _Pragma("unroll")                                                             \
        for (int jn = 0; jn < 2; ++jn) {                                              \
            f32x4 bb = *(const f32x4*)&b1[(CH) * 128 + w * 32 + jn * 16 + lg * 4];    \
            _Pragma("unroll")                                                         \
            for (int mi = 0; mi < 4; ++mi) HACC[jn][mi] = bb;                         \
        }                                                                             \
        const ushort_t* w1p = W1f + ((size_t)((CH) * 4 + w) * 16) * 512 + lane * 8;   \
        __builtin_amdgcn_s_setprio(1);                                                \
        _Pragma("unroll")                                                             \
        for (int kk = 0; kk < 8; ++kk) {                                              \
            bf16x8 xf[4];                                                             \
            _Pragma("unroll")                                                         \
            for (int mi = 0; mi < 4; ++mi)                                            \
                xf[mi] = *(const bf16x8*)&x2mb[mi * 4096 + kk * 512 + lane * 8];      \
            _Pragma("unroll")                                                         \
            for (int jn = 0; jn < 2; ++jn) {                                          \
                bf16x8 wf = *(const bf16x8*)(w1p + (kk * 2 + jn) * 512);              \
                _Pragma("unroll")                                                     \
                for (int mi = 0; mi < 4; ++mi)                                        \
                    HACC[jn][mi] = __builtin_amdgcn_mfma_f32_16x16x32_bf16(wf, xf[mi], HACC[jn][mi], 0, 0, 0); \
            }                                                                         \
        }                                                                             \
        __builtin_amdgcn_s_setprio(0);                                                \
    }

#define GELU_STORE(HACC) {                                                            \
        _Pragma("unroll")                                                             \
        for (int jn = 0; jn < 2; ++jn)                                                \
            _Pragma("unroll")                                                         \
            for (int mi = 0; mi < 4; ++mi) {                                          \
                uint2 o;                                                              \
                o.x = pk2(gelu_f(HACC[jn][mi][0]), gelu_f(HACC[jn][mi][1]));          \
                o.y = pk2(gelu_f(HACC[jn][mi][2]), gelu_f(HACC[jn][mi][3]));          \
                *(uint2*)&hmb[hwbase + jn * 256 + mi * 512] = o;                      \
            }                                                                         \
    }

#define GEMM2_CHUNK(CH) {                                                             \
        bf16x8 b2r[4][2];                                                             \
        const ushort_t* w2p = W2f + (((size_t)((CH) * 4 + w) * 4) * 2) * 512 + lane * 8; \
        _Pragma("unroll")                                                             \
        for (int kk = 0; kk < 4; ++kk)                                                \
            _Pragma("unroll")                                                         \
            for (int jy = 0; jy < 2; ++jy)                                            \
                b2r[kk][jy] = *(const bf16x8*)(w2p + (kk * 2 + jy) * 512);            \
        __builtin_amdgcn_s_setprio(1);                                                \
        _Pragma("unroll")                                                             \
        for (int kk = 0; kk < 4; ++kk) {                                              \
            bf16x8 a4[4];                                                             \
            _Pragma("unroll")                                                         \
            for (int mi = 0; mi < 4; ++mi)                                            \
                a4[mi] = *(const bf16x8*)&hmb[kk * 2048 + mi * 512 + lane * 8];       \
            _Pragma("unroll")                                                         \
            for (int jy = 0; jy < 2; ++jy)                                            \
                _Pragma("unroll")                                                     \
                for (int mi = 0; mi < 4; ++mi)                                        \
                    yacc[mi][jy] = __builtin_amdgcn_mfma_f32_16x16x32_bf16(a4[mi], b2r[kk][jy], yacc[mi][jy], 0, 0, 0); \
        }                                                                             \
        __builtin_amdgcn_s_setprio(0);                                                \
    }

    f32x4 haccA[2][4], haccB[2][4];
    GEMM1_INTO(haccA, 0);
#pragma unroll
    for (int cc = 0; cc < 4; ++cc) {
        int ch = cc * 2;
        __syncthreads();            // prev GEMM2 hmb reads complete
        GELU_STORE(haccA);
        __syncthreads();            // hmb(ch) published
        GEMM1_INTO(haccB, ch + 1);  // independent MFMA fills the region
        GEMM2_CHUNK(ch);
        __syncthreads();            // GEMM2(ch) hmb reads complete
        GELU_STORE(haccB);
        __syncthreads();            // hmb(ch+1) published
        if (cc < 3) GEMM1_INTO(haccA, ch + 2);
        GEMM2_CHUNK(ch + 1);
    }
#undef GEMM1_INTO
#undef GELU_STORE
#undef GEMM2_CHUNK

    // ---- epilogue: residual + store + BN partials ----
    float sacc[2] = {0.f, 0.f}, qacc[2] = {0.f, 0.f};
#pragma unroll
    for (int mi = 0; mi < 4; ++mi)
#pragma unroll
        for (int jy = 0; jy < 2; ++jy)
#pragma unroll
            for (int r = 0; r < 4; ++r) {
                int gr = rowbase + mi * 16 + lg * 4 + r;
                int gc = w * 32 + jy * 16 + lr;
                float val = yacc[mi][jy][r] + input[(size_t)gr * 128 + gc];
                out[(size_t)gr * 128 + gc] = val;
                sacc[jy] += val;
                qacc[jy] += val * val;
            }
#pragma unroll
    for (int jy = 0; jy < 2; ++jy) {
        float s = sacc[jy], q = qacc[jy];
        s += __shfl_xor(s, 16); s += __shfl_xor(s, 32);
        q += __shfl_xor(q, 16); q += __shfl_xor(q, 32);
        if (lg == 0) {
            atomicAdd(&bn_sum[w * 32 + jy * 16 + lr], s);
            atomicAdd(&bn_sq[w * 32 + jy * 16 + lr], q);
        }
    }
}

// ---------- BN finalize + apply (fused, in place) ----------
__global__ __launch_bounds__(256) void k_bnapply(float* __restrict__ out,
                                                 const float* __restrict__ bn_sum,
                                                 const float* __restrict__ bn_sq,
                                                 const float* __restrict__ gamma,
                                                 const float* __restrict__ beta) {
    size_t idx = (size_t)blockIdx.x * 256 + threadIdx.x;
    int c = (int)((idx * 4) & 127);
    float4 v = *(float4*)&out[idx * 4];
    float4 sm = *(const float4*)&bn_sum[c];
    float4 sq = *(const float4*)&bn_sq[c];
    float4 gm = *(const float4*)&gamma[c];
    float4 bt = *(const float4*)&beta[c];
    const float inv = 1.0f / CNT;
    float4 sc, sh;
#pragma unroll
    for (int j = 0; j < 4; ++j) {
        float mean = ((const float*)&sm)[j] * inv;
        float var  = ((const float*)&sq)[j] * inv - mean * mean;
        float s = ((const float*)&gm)[j] * rsqrtf(var + 1e-5f);
        ((float*)&sc)[j] = s;
        ((float*)&sh)[j] = ((const float*)&bt)[j] - mean * s;
    }
    v.x = fmaf(v.x, sc.x, sh.x);
    v.y = fmaf(v.y, sc.y, sh.y);
    v.z = fmaf(v.z, sc.z, sh.z);
    v.w = fmaf(v.w, sc.w, sh.w);
    *(float4*)&out[idx * 4] = v;
}

extern "C" void kernel_launch(void* const* d_in, const int* in_sizes, int n_in,
                              void* d_out, int out_size, void* d_ws, size_t ws_size,
                              hipStream_t stream) {
    const float* input    = (const float*)d_in[0];
    const float* Wv       = (const float*)d_in[1];
    const float* bv       = (const float*)d_in[2];
    const float* adaptive = (const float*)d_in[3];
    const float* cores    = (const float*)d_in[4];
    const float* W1       = (const float*)d_in[5];
    const float* b1       = (const float*)d_in[6];
    const float* W2       = (const float*)d_in[7];
    const float* b2       = (const float*)d_in[8];
    const float* gamma    = (const float*)d_in[9];
    const float* beta     = (const float*)d_in[10];
    float* out = (float*)d_out;
    float* ws  = (float*)d_ws;

    float*    aff    = ws;                           // 524288 f
    ushort_t* a_n2c  = (ushort_t*)(ws + 524288);     // 524288 us
    ushort_t* a_c2nT = (ushort_t*)(ws + 786432);     // 524288 us
    ushort_t* T1t    = (ushort_t*)(ws + 1048576);    // 1572864 us
    ushort_t* W1f    = (ushort_t*)(ws + 1835008);    // 262144 us
    ushort_t* W2f    = (ushort_t*)(ws + 1966080);    // 131072 us
    ushort_t* WvT    = (ushort_t*)(ws + 2031616);    // 16384 us
    float* bn_sum    = ws + 2039808;
    float* bn_sq     = bn_sum + 128;
    float* T1p       = ws + 2097152;                 // 4 x T1SZ f

    k_sm_n   <<<512, 256, 0, stream>>>(cores, adaptive, aff, a_n2c);
    k_prep   <<<325, 256, 0, stream>>>(aff, Wv, W1, W2, a_c2nT, WvT, W1f, W2f, bn_sum);
    k_vs1    <<<dim3(BT, 4), 256, 0, stream>>>(input, WvT, bv, a_n2c, T1p);
    k_t1conv <<<1536, 256, 0, stream>>>(T1p, T1t);
    k_ffn    <<<dim3(16, BT), 256, 0, stream>>>(input, a_c2nT, T1t, W1f, W2f,
                                                b1, b2, out, bn_sum, bn_sq);
    k_bnapply<<<(out_size / 4) / 256, 256, 0, stream>>>(out, bn_sum, bn_sq, gamma, beta);
}